// Round 1
// baseline (4167.060 us; speedup 1.0000x reference)
//
#include <hip/hip_runtime.h>
#include <hip/hip_fp16.h>

typedef _Float16 f16x8 __attribute__((ext_vector_type(8)));
typedef float f32x4 __attribute__((ext_vector_type(4)));
typedef unsigned int u32x4 __attribute__((ext_vector_type(4)));
typedef unsigned int u32x2 __attribute__((ext_vector_type(2)));
typedef unsigned long long u64;

static constexpr int T_SEQ = 512;
static constexpr int BATCH = 64;
static constexpr int HID   = 512;
static constexpr int VOC   = 128;

// ---- fp16 arena element offsets ----
static constexpr int AOFF_EMB  = 0;        // 128*256
static constexpr int AOFF_WXH0 = 32768;    // 512*256
static constexpr int AOFF_WHH0 = 163840;   // 512*512
static constexpr int AOFF_WXH1 = 425984;   // 512*512
static constexpr int AOFF_WHH1 = 688128;   // 512*512
static constexpr int AOFF_WHY  = 950272;   // 128*512
static constexpr int ATOT      = 1015808;

// ---- ws byte offsets ----
static constexpr size_t OFF_FLAGS = 0;                    // 2*16 regions * 64 ints
static constexpr size_t OFF_RING  = 16384;                // 2 * 32768 u64 = 512 KB
static constexpr size_t OFF_ARENA = 1u << 20;
static constexpr size_t PLANE_B   = (size_t)T_SEQ * BATCH * HID * 2;  // 32 MB
static constexpr size_t OFF_XW0   = 4u << 20;
static constexpr size_t OFF_XW1   = OFF_XW0 + PLANE_B;
static constexpr size_t OFF_H0A   = OFF_XW1 + PLANE_B;    // A-frag layout [t][g][kc][lane][8]
static constexpr size_t OFF_H1A   = OFF_H0A + PLANE_B;    // ends ~132 MB

__device__ __forceinline__ unsigned short h2u(_Float16 h) {
  union { _Float16 h; unsigned short u; } c; c.h = h; return c.u;
}
__device__ __forceinline__ _Float16 u2h(unsigned short u) {
  union { unsigned short u; _Float16 h; } c; c.u = u; return c.h;
}
__device__ __forceinline__ float fast_tanh(float x) {
  float e = __expf(2.0f * x);
  return 1.0f - 2.0f * __builtin_amdgcn_rcpf(e + 1.0f);
}

// fp32 params -> fp16 arena; zero flags (2 layers x 16 regions x 64 ints).
__global__ __launch_bounds__(256) void canon_kernel(
    const float* p0, const float* p1, const float* p2, const float* p3,
    const float* p4, const float* p5, _Float16* __restrict__ dst,
    int* __restrict__ flags) {
  if (blockIdx.x == 0)
    for (int i = threadIdx.x; i < 2 * 16 * 64; i += 256) flags[i] = 0;
  const float* srcs[6] = {p0, p1, p2, p3, p4, p5};
  const int ns[6] = {32768, 131072, 262144, 262144, 262144, 65536};
  for (int i = blockIdx.x * 256 + threadIdx.x; i < ATOT; i += gridDim.x * 256) {
    int off = i, s = 0;
    while (off >= ns[s]) { off -= ns[s]; ++s; }
    dst[i] = (_Float16)srcs[s][off];
  }
}

// xwf0[t][n][b] = emb[x[b,t]][:] . Wxh0[n][:] + bh0[n].  Grid (512, 8) x 256.
__global__ __launch_bounds__(256) void xw0_kernel(
    const int* __restrict__ x, const _Float16* __restrict__ emb,
    const _Float16* __restrict__ Wxh, const float* __restrict__ bh,
    _Float16* __restrict__ xwf) {
  __shared__ _Float16 Bs[64][264];
  const int t = blockIdx.x, n0 = blockIdx.y * 64, tid = threadIdx.x;
#pragma unroll
  for (int rep = 0; rep < 8; ++rep) {
    int flat = rep * 256 + tid;
    int row = flat >> 5, c8 = flat & 31;
    *(f16x8*)&Bs[row][c8 * 8] = *(const f16x8*)&Wxh[(size_t)(n0 + row) * 256 + c8 * 8];
  }
  __syncthreads();
  const int wv = tid >> 6, lane = tid & 63, l15 = lane & 15, quad = lane >> 4;
  const int b = wv * 16 + l15;
  const int idx = x[b * 512 + t];
  f32x4 acc[4];
#pragma unroll
  for (int nt = 0; nt < 4; ++nt) { float bv = bh[n0 + nt * 16 + l15]; acc[nt] = {bv, bv, bv, bv}; }
#pragma unroll
  for (int kc = 0; kc < 8; ++kc) {
    f16x8 a = *(const f16x8*)&emb[(size_t)idx * 256 + kc * 32 + quad * 8];
#pragma unroll
    for (int nt = 0; nt < 4; ++nt) {
      f16x8 bf = *(const f16x8*)&Bs[nt * 16 + l15][kc * 32 + quad * 8];
      acc[nt] = __builtin_amdgcn_mfma_f32_16x16x32_f16(a, bf, acc[nt], 0, 0, 0);
    }
  }
#pragma unroll
  for (int nt = 0; nt < 4; ++nt) {
    unsigned int lo = (unsigned int)h2u((_Float16)acc[nt][0]) |
                      ((unsigned int)h2u((_Float16)acc[nt][1]) << 16);
    unsigned int hi = (unsigned int)h2u((_Float16)acc[nt][2]) |
                      ((unsigned int)h2u((_Float16)acc[nt][3]) << 16);
    u32x2 pk = {lo, hi};
    *(u32x2*)&xwf[(size_t)t * 32768 + (size_t)(n0 + nt * 16 + l15) * 64 + wv * 16 + quad * 4] = pk;
  }
}

// xwf1[t][n][b] = h0[t,b][:] . Wxh1[n][:] + bh1[n]; h0 read in A-frag layout.
// Grid (512, 16) x 256.
__global__ __launch_bounds__(256) void xw1_kernel(
    const _Float16* __restrict__ h0A, const _Float16* __restrict__ Wxh,
    const float* __restrict__ bh, _Float16* __restrict__ xwf) {
  __shared__ _Float16 Bs[32][520];
  const int t = blockIdx.x, n0 = blockIdx.y * 32, tid = threadIdx.x;
#pragma unroll
  for (int rep = 0; rep < 8; ++rep) {
    int flat = rep * 256 + tid;
    int row = flat >> 6, c8 = flat & 63;
    *(f16x8*)&Bs[row][c8 * 8] = *(const f16x8*)&Wxh[(size_t)(n0 + row) * 512 + c8 * 8];
  }
  __syncthreads();
  const int wv = tid >> 6, lane = tid & 63, l15 = lane & 15, quad = lane >> 4;
  f32x4 acc[2];
#pragma unroll
  for (int nt = 0; nt < 2; ++nt) { float bv = bh[n0 + nt * 16 + l15]; acc[nt] = {bv, bv, bv, bv}; }
#pragma unroll
  for (int kc = 0; kc < 16; ++kc) {
    // identity A-frag load: group g = wv (batches 16wv..16wv+16)
    f16x8 a = *(const f16x8*)&h0A[(((size_t)t * 4 + wv) * 16 + kc) * 512 + lane * 8];
#pragma unroll
    for (int nt = 0; nt < 2; ++nt) {
      f16x8 bf = *(const f16x8*)&Bs[nt * 16 + l15][kc * 32 + quad * 8];
      acc[nt] = __builtin_amdgcn_mfma_f32_16x16x32_f16(a, bf, acc[nt], 0, 0, 0);
    }
  }
#pragma unroll
  for (int nt = 0; nt < 2; ++nt) {
    unsigned int lo = (unsigned int)h2u((_Float16)acc[nt][0]) |
                      ((unsigned int)h2u((_Float16)acc[nt][1]) << 16);
    unsigned int hi = (unsigned int)h2u((_Float16)acc[nt][2]) |
                      ((unsigned int)h2u((_Float16)acc[nt][3]) << 16);
    u32x2 pk = {lo, hi};
    *(u32x2*)&xwf[(size_t)t * 32768 + (size_t)(n0 + nt * 16 + l15) * 64 + wv * 16 + quad * 4] = pk;
  }
}

// Quad recurrence: grid 16 x 512. Block b: group g=b&3 (batches 16g..+16),
// quarter q=b>>2 (cols 128q..+128). Wave owns 16 cols -> 64 weight VGPRs
// loaded in ROTATED kc order (Bw[i] = kc (q*4+i)&15) so own-quarter kcs are
// Bw[0..3] with static indices (runtime VGPR-array index => scratch).
//
// Sync overhaul vs previous version:
//  * per-quarter COUNTER (was flag): each wave fetch_add(1, RELEASE) right
//    after its own ring stores; publish no longer waits on bar3/slowest wave.
//    bar3 deleted (intra-block alds ordering already covered by bar1/bar2).
//  * consumer polls all 3 partner counters with bitwise | (was short-circuit
//    || => 3 serialized fabric latencies); loads issue back-to-back, one RT.
//  * acquire fence after poll orders the relaxed ring loads.
//  * own-quarter 4 MFMAs issue BEFORE the poll (own h_{t-1} section is staged
//    locally at t-1); ring loads are issued into temps, the LDS fill waits on
//    them after.
__global__ __launch_bounds__(512, 1) void rnn_quad_kernel(
    const _Float16* __restrict__ Whh,
    const _Float16* __restrict__ xwf,
    _Float16* __restrict__ hA,          // [t][g][kc][lane][8] A-frag dump (by q0)
    u64* __restrict__ ring,             // [(g*4+q)][slot][512]
    int* __restrict__ flags)            // [(g*4+q)*64] counters
{
  const int bidx = blockIdx.x, g = bidx & 3, q = bidx >> 2;
  const int tid = threadIdx.x, lane = tid & 63, wv = tid >> 6;
  const int l15 = lane & 15, quad = lane >> 4;
  const int n0 = q * 128 + wv * 16;

  __shared__ _Float16 alds[16 * 512];
  u64* aldsu = (u64*)alds;

  // 64 weight VGPRs/wave, rotated: Bw[i] holds kc=(q*4+i)&15.
  u32x4 Bw[16];
#pragma unroll
  for (int i = 0; i < 16; ++i) {
    const int kc = (q * 4 + i) & 15;
    Bw[i] = *(const u32x4*)&Whh[(size_t)(n0 + l15) * 512 + kc * 32 + quad * 8];
  }
#pragma unroll
  for (int i = 0; i < 16; ++i)
    asm volatile("" : "+v"(Bw[i]));

  int* pflag[3];
  u64* pring[3];
  int pquar[3];
  {
    int pi = 0;
    for (int qq = 0; qq < 4; ++qq)
      if (qq != q) {
        pflag[pi] = flags + (g * 4 + qq) * 64;
        pring[pi] = ring + (size_t)(g * 4 + qq) * 4 * 512;
        pquar[pi] = qq;
        ++pi;
      }
  }
  int* myflag = flags + (g * 4 + q) * 64;
  u64* myring = ring + (size_t)(g * 4 + q) * 4 * 512;

  const _Float16* xwb = xwf + (size_t)(n0 + l15) * 64 + g * 16 + quad * 4;
  u32x2 pfx = *(const u32x2*)xwb;

  for (int t = 0; t < T_SEQ; ++t) {
    f32x4 acc;
    acc[0] = (float)u2h((unsigned short)(pfx.x & 0xFFFFu));
    acc[1] = (float)u2h((unsigned short)(pfx.x >> 16));
    acc[2] = (float)u2h((unsigned short)(pfx.y & 0xFFFFu));
    acc[3] = (float)u2h((unsigned short)(pfx.y >> 16));
    if (t + 1 < T_SEQ) pfx = *(const u32x2*)(xwb + (size_t)(t + 1) * 32768);

    if (t > 0) {
      // own-quarter kcs first: A from own alds section (staged at t-1, visible
      // since bar2(t-1); not overwritten until stage(t) which is after bar1(t)).
#pragma unroll
      for (int i = 0; i < 4; ++i) {
        const int kc = q * 4 + i;
        f16x8 a = *(const f16x8*)&alds[kc * 512 + lane * 8];
        acc = __builtin_amdgcn_mfma_f32_16x16x32_f16(
            a, __builtin_bit_cast(f16x8, Bw[i]), acc, 0, 0, 0);
      }

      // wait for partners' h_{t-1}: 3 counter loads issued in parallel (bitwise |).
      const int tgt = 8 * t;  // 8 waves/quarter have published step t-1
      while ((__hip_atomic_load(pflag[0], __ATOMIC_RELAXED, __HIP_MEMORY_SCOPE_AGENT) < tgt) |
             (__hip_atomic_load(pflag[1], __ATOMIC_RELAXED, __HIP_MEMORY_SCOPE_AGENT) < tgt) |
             (__hip_atomic_load(pflag[2], __ATOMIC_RELAXED, __HIP_MEMORY_SCOPE_AGENT) < tgt))
        __builtin_amdgcn_s_sleep(1);
      __builtin_amdgcn_fence(__ATOMIC_ACQUIRE, "agent");

      const int slot = (t - 1) & 3;
      u64 v0 = __hip_atomic_load(pring[0] + (size_t)slot * 512 + tid,
                                 __ATOMIC_RELAXED, __HIP_MEMORY_SCOPE_AGENT);
      u64 v1 = __hip_atomic_load(pring[1] + (size_t)slot * 512 + tid,
                                 __ATOMIC_RELAXED, __HIP_MEMORY_SCOPE_AGENT);
      u64 v2 = __hip_atomic_load(pring[2] + (size_t)slot * 512 + tid,
                                 __ATOMIC_RELAXED, __HIP_MEMORY_SCOPE_AGENT);
      aldsu[pquar[0] * 512 + tid] = v0;
      aldsu[pquar[1] * 512 + tid] = v1;
      aldsu[pquar[2] * 512 + tid] = v2;
      __syncthreads();  // bar_A: alds(t-1) complete

      if (q == 0) {     // dump h_{t-1} fragplane (16 KB) for xw1/logits/hlast
        u64* dst = (u64*)hA + ((size_t)(t - 1) * 4 + g) * 2048;   // plane = 2048 u64
#pragma unroll
        for (int i = 0; i < 4; ++i)
          dst[tid + 512 * i] = aldsu[tid + 512 * i];
      }

      // partner kcs in rotated order (static Bw index, runtime LDS addr).
#pragma unroll
      for (int i = 4; i < 16; ++i) {
        const int kc = (q * 4 + i) & 15;
        f16x8 a = *(const f16x8*)&alds[kc * 512 + lane * 8];
        acc = __builtin_amdgcn_mfma_f32_16x16x32_f16(
            a, __builtin_bit_cast(f16x8, Bw[i]), acc, 0, 0, 0);
      }
      __syncthreads();  // bar1: alds reads done before overwrite
    }

    // tanh + stage own cols of h_t into alds in A-frag order
    {
      const int n = n0 + l15;
      const int kc = n >> 5, qd = (n >> 3) & 3, j = n & 7;
#pragma unroll
      for (int r = 0; r < 4; ++r)
        alds[kc * 512 + (qd * 16 + quad * 4 + r) * 8 + j] = (_Float16)fast_tanh(acc[r]);
    }
    __syncthreads();    // bar2: staging visible
    {
      u64 v = aldsu[q * 512 + tid];
      __hip_atomic_store(myring + (size_t)(t & 3) * 512 + tid, v,
                         __ATOMIC_RELAXED, __HIP_MEMORY_SCOPE_AGENT);
    }
    // per-wave publish: release-add orders THIS wave's ring stores (release
    // => s_waitcnt vmcnt(0) before the atomic). No bar3 needed.
    if (lane == 0)
      __hip_atomic_fetch_add(myflag, 1, __ATOMIC_RELEASE, __HIP_MEMORY_SCOPE_AGENT);
  }

  // epilogue: q0 assembles and dumps h_{T-1}
  if (q == 0) {
    const int tgt = 8 * T_SEQ;
    while ((__hip_atomic_load(pflag[0], __ATOMIC_RELAXED, __HIP_MEMORY_SCOPE_AGENT) < tgt) |
           (__hip_atomic_load(pflag[1], __ATOMIC_RELAXED, __HIP_MEMORY_SCOPE_AGENT) < tgt) |
           (__hip_atomic_load(pflag[2], __ATOMIC_RELAXED, __HIP_MEMORY_SCOPE_AGENT) < tgt))
      __builtin_amdgcn_s_sleep(1);
    __builtin_amdgcn_fence(__ATOMIC_ACQUIRE, "agent");
    const int slot = (T_SEQ - 1) & 3;
#pragma unroll
    for (int p = 0; p < 3; ++p) {
      u64 v = __hip_atomic_load(pring[p] + (size_t)slot * 512 + tid,
                                __ATOMIC_RELAXED, __HIP_MEMORY_SCOPE_AGENT);
      aldsu[pquar[p] * 512 + tid] = v;
    }
    __syncthreads();
    u64* dst = (u64*)hA + ((size_t)(T_SEQ - 1) * 4 + g) * 2048;   // plane = 2048 u64
#pragma unroll
    for (int i = 0; i < 4; ++i)
      dst[tid + 512 * i] = aldsu[tid + 512 * i];
  }
}

// logits[b][t][v] = h1[t,b][:] . Why[v][:] + by[v]; h1 in A-frag layout. Grid 512 x 256.
__global__ __launch_bounds__(256) void logits_kernel(
    const _Float16* __restrict__ h1A, const _Float16* __restrict__ Why,
    const float* __restrict__ by, float* __restrict__ out) {
  const int t = blockIdx.x;
  const int wv = threadIdx.x >> 6, lane = threadIdx.x & 63;
  const int l15 = lane & 15, quad = lane >> 4, bb = wv * 16;
  f32x4 acc[8];
#pragma unroll
  for (int vt = 0; vt < 8; ++vt) { float bv = by[vt * 16 + l15]; acc[vt] = {bv, bv, bv, bv}; }
#pragma unroll
  for (int kc = 0; kc < 16; ++kc) {
    f16x8 a = *(const f16x8*)&h1A[(((size_t)t * 4 + wv) * 16 + kc) * 512 + lane * 8];
#pragma unroll
    for (int vt = 0; vt < 8; ++vt) {
      f16x8 b = *(const f16x8*)&Why[(size_t)(vt * 16 + l15) * 512 + kc * 32 + quad * 8];
      acc[vt] = __builtin_amdgcn_mfma_f32_16x16x32_f16(a, b, acc[vt], 0, 0, 0);
    }
  }
#pragma unroll
  for (int vt = 0; vt < 8; ++vt)
#pragma unroll
    for (int r = 0; r < 4; ++r)
      out[((size_t)(bb + quad * 4 + r) * 512 + t) * 128 + vt * 16 + l15] = acc[vt][r];
}

// h_last from A-frag dumps at t=511. One element each per layer.
__global__ void hlast_kernel(const _Float16* __restrict__ h0A,
                             const _Float16* __restrict__ h1A,
                             float* __restrict__ out) {
  const size_t LOG = (size_t)BATCH * T_SEQ * VOC;
  const size_t HL = (size_t)BATCH * HID;
  int tid = blockIdx.x * 256 + threadIdx.x;
  if (tid < (int)HL) {
    const int b = tid >> 9, n = tid & 511;
    const int gg = b >> 4, m = b & 15;
    const int kc = n >> 5, qd = (n >> 3) & 3, j = n & 7;
    const size_t idx = (((size_t)(T_SEQ - 1) * 4 + gg) * 16 + kc) * 512 + (qd * 16 + m) * 8 + j;
    out[LOG + tid]      = (float)h0A[idx];
    out[LOG + HL + tid] = (float)h1A[idx];
  }
}

extern "C" void kernel_launch(void* const* d_in, const int* in_sizes, int n_in,
                              void* d_out, int out_size, void* d_ws, size_t ws_size,
                              hipStream_t stream) {
  const int* x = (const int*)d_in[0];
  float* out = (float*)d_out;
  char* ws = (char*)d_ws;
  int* flags = (int*)(ws + OFF_FLAGS);
  u64* ring = (u64*)(ws + OFF_RING);      // 2 layers x 32768 u64
  _Float16* arena = (_Float16*)(ws + OFF_ARENA);
  _Float16* xw0f = (_Float16*)(ws + OFF_XW0);
  _Float16* xw1f = (_Float16*)(ws + OFF_XW1);
  _Float16* h0A  = (_Float16*)(ws + OFF_H0A);
  _Float16* h1A  = (_Float16*)(ws + OFF_H1A);

  canon_kernel<<<512, 256, 0, stream>>>(
      (const float*)d_in[1], (const float*)d_in[2], (const float*)d_in[3],
      (const float*)d_in[5], (const float*)d_in[6], (const float*)d_in[8],
      arena, flags);

  xw0_kernel<<<dim3(512, 8), 256, 0, stream>>>(
      x, arena + AOFF_EMB, arena + AOFF_WXH0, (const float*)d_in[4], xw0f);

  rnn_quad_kernel<<<16, 512, 0, stream>>>(
      arena + AOFF_WHH0, xw0f, h0A, ring, flags);

  xw1_kernel<<<dim3(512, 16), 256, 0, stream>>>(
      h0A, arena + AOFF_WXH1, (const float*)d_in[7], xw1f);

  rnn_quad_kernel<<<16, 512, 0, stream>>>(
      arena + AOFF_WHH1, xw1f, h1A, ring + 32768, flags + 16 * 64);

  logits_kernel<<<512, 256, 0, stream>>>(
      h1A, arena + AOFF_WHY, (const float*)d_in[9], out);

  hlast_kernel<<<(BATCH * HID + 255) / 256, 256, 0, stream>>>(h0A, h1A, out);
}

// Round 4
// 2537.417 us; speedup vs baseline: 1.6422x; 1.6422x over previous
//
#include <hip/hip_runtime.h>
#include <hip/hip_fp16.h>

typedef _Float16 f16x8 __attribute__((ext_vector_type(8)));
typedef float f32x4 __attribute__((ext_vector_type(4)));
typedef unsigned int u32x4 __attribute__((ext_vector_type(4)));
typedef unsigned int u32x2 __attribute__((ext_vector_type(2)));
typedef unsigned long long u64;

static constexpr int T_SEQ = 512;
static constexpr int BATCH = 64;
static constexpr int HID   = 512;
static constexpr int VOC   = 128;

// ---- fp16 arena element offsets ----
static constexpr int AOFF_EMB  = 0;        // 128*256
static constexpr int AOFF_WXH0 = 32768;    // 512*256
static constexpr int AOFF_WHH0 = 163840;   // 512*512
static constexpr int AOFF_WXH1 = 425984;   // 512*512
static constexpr int AOFF_WHH1 = 688128;   // 512*512
static constexpr int AOFF_WHY  = 950272;   // 128*512
static constexpr int ATOT      = 1015808;

// ---- ws byte offsets ----
static constexpr size_t OFF_FLAGS = 0;                    // 2*16 regions * 64 ints
static constexpr size_t OFF_RING  = 16384;                // 2 * 32768 u64 = 512 KB
static constexpr size_t OFF_ARENA = 1u << 20;
static constexpr size_t PLANE_B   = (size_t)T_SEQ * BATCH * HID * 2;  // 32 MB
static constexpr size_t OFF_XW0   = 4u << 20;
static constexpr size_t OFF_XW1   = OFF_XW0 + PLANE_B;
static constexpr size_t OFF_H0A   = OFF_XW1 + PLANE_B;    // A-frag layout [t][g][kc][lane][8]
static constexpr size_t OFF_H1A   = OFF_H0A + PLANE_B;    // ends ~132 MB

__device__ __forceinline__ unsigned short h2u(_Float16 h) {
  union { _Float16 h; unsigned short u; } c; c.h = h; return c.u;
}
__device__ __forceinline__ _Float16 u2h(unsigned short u) {
  union { unsigned short u; _Float16 h; } c; c.u = u; return c.h;
}
__device__ __forceinline__ float fast_tanh(float x) {
  float e = __expf(2.0f * x);
  return 1.0f - 2.0f * __builtin_amdgcn_rcpf(e + 1.0f);
}

// fp32 params -> fp16 arena; zero flags (2 layers x 16 regions x 64 ints).
__global__ __launch_bounds__(256) void canon_kernel(
    const float* p0, const float* p1, const float* p2, const float* p3,
    const float* p4, const float* p5, _Float16* __restrict__ dst,
    int* __restrict__ flags) {
  if (blockIdx.x == 0)
    for (int i = threadIdx.x; i < 2 * 16 * 64; i += 256) flags[i] = 0;
  const float* srcs[6] = {p0, p1, p2, p3, p4, p5};
  const int ns[6] = {32768, 131072, 262144, 262144, 262144, 65536};
  for (int i = blockIdx.x * 256 + threadIdx.x; i < ATOT; i += gridDim.x * 256) {
    int off = i, s = 0;
    while (off >= ns[s]) { off -= ns[s]; ++s; }
    dst[i] = (_Float16)srcs[s][off];
  }
}

// xwf0[t][n][b] = emb[x[b,t]][:] . Wxh0[n][:] + bh0[n].  Grid (512, 8) x 256.
__global__ __launch_bounds__(256) void xw0_kernel(
    const int* __restrict__ x, const _Float16* __restrict__ emb,
    const _Float16* __restrict__ Wxh, const float* __restrict__ bh,
    _Float16* __restrict__ xwf) {
  __shared__ _Float16 Bs[64][264];
  const int t = blockIdx.x, n0 = blockIdx.y * 64, tid = threadIdx.x;
#pragma unroll
  for (int rep = 0; rep < 8; ++rep) {
    int flat = rep * 256 + tid;
    int row = flat >> 5, c8 = flat & 31;
    *(f16x8*)&Bs[row][c8 * 8] = *(const f16x8*)&Wxh[(size_t)(n0 + row) * 256 + c8 * 8];
  }
  __syncthreads();
  const int wv = tid >> 6, lane = tid & 63, l15 = lane & 15, quad = lane >> 4;
  const int b = wv * 16 + l15;
  const int idx = x[b * 512 + t];
  f32x4 acc[4];
#pragma unroll
  for (int nt = 0; nt < 4; ++nt) { float bv = bh[n0 + nt * 16 + l15]; acc[nt] = {bv, bv, bv, bv}; }
#pragma unroll
  for (int kc = 0; kc < 8; ++kc) {
    f16x8 a = *(const f16x8*)&emb[(size_t)idx * 256 + kc * 32 + quad * 8];
#pragma unroll
    for (int nt = 0; nt < 4; ++nt) {
      f16x8 bf = *(const f16x8*)&Bs[nt * 16 + l15][kc * 32 + quad * 8];
      acc[nt] = __builtin_amdgcn_mfma_f32_16x16x32_f16(a, bf, acc[nt], 0, 0, 0);
    }
  }
#pragma unroll
  for (int nt = 0; nt < 4; ++nt) {
    unsigned int lo = (unsigned int)h2u((_Float16)acc[nt][0]) |
                      ((unsigned int)h2u((_Float16)acc[nt][1]) << 16);
    unsigned int hi = (unsigned int)h2u((_Float16)acc[nt][2]) |
                      ((unsigned int)h2u((_Float16)acc[nt][3]) << 16);
    u32x2 pk = {lo, hi};
    *(u32x2*)&xwf[(size_t)t * 32768 + (size_t)(n0 + nt * 16 + l15) * 64 + wv * 16 + quad * 4] = pk;
  }
}

// xwf1[t][n][b] = h0[t,b][:] . Wxh1[n][:] + bh1[n]; h0 read in A-frag layout.
// Grid (512, 16) x 256.
__global__ __launch_bounds__(256) void xw1_kernel(
    const _Float16* __restrict__ h0A, const _Float16* __restrict__ Wxh,
    const float* __restrict__ bh, _Float16* __restrict__ xwf) {
  __shared__ _Float16 Bs[32][520];
  const int t = blockIdx.x, n0 = blockIdx.y * 32, tid = threadIdx.x;
#pragma unroll
  for (int rep = 0; rep < 8; ++rep) {
    int flat = rep * 256 + tid;
    int row = flat >> 6, c8 = flat & 63;
    *(f16x8*)&Bs[row][c8 * 8] = *(const f16x8*)&Wxh[(size_t)(n0 + row) * 512 + c8 * 8];
  }
  __syncthreads();
  const int wv = tid >> 6, lane = tid & 63, l15 = lane & 15, quad = lane >> 4;
  f32x4 acc[2];
#pragma unroll
  for (int nt = 0; nt < 2; ++nt) { float bv = bh[n0 + nt * 16 + l15]; acc[nt] = {bv, bv, bv, bv}; }
#pragma unroll
  for (int kc = 0; kc < 16; ++kc) {
    // identity A-frag load: group g = wv (batches 16wv..16wv+16)
    f16x8 a = *(const f16x8*)&h0A[(((size_t)t * 4 + wv) * 16 + kc) * 512 + lane * 8];
#pragma unroll
    for (int nt = 0; nt < 2; ++nt) {
      f16x8 bf = *(const f16x8*)&Bs[nt * 16 + l15][kc * 32 + quad * 8];
      acc[nt] = __builtin_amdgcn_mfma_f32_16x16x32_f16(a, bf, acc[nt], 0, 0, 0);
    }
  }
#pragma unroll
  for (int nt = 0; nt < 2; ++nt) {
    unsigned int lo = (unsigned int)h2u((_Float16)acc[nt][0]) |
                      ((unsigned int)h2u((_Float16)acc[nt][1]) << 16);
    unsigned int hi = (unsigned int)h2u((_Float16)acc[nt][2]) |
                      ((unsigned int)h2u((_Float16)acc[nt][3]) << 16);
    u32x2 pk = {lo, hi};
    *(u32x2*)&xwf[(size_t)t * 32768 + (size_t)(n0 + nt * 16 + l15) * 64 + wv * 16 + quad * 4] = pk;
  }
}

// Quad recurrence: grid 16 x 512. Block b: group g=b&3 (batches 16g..+16),
// quarter q=b>>2 (cols 128q..+128). Wave owns 16 cols -> 64 weight VGPRs,
// loaded in ROTATED kc order (Bw[i] = kc (q*4+i)&15) so own-quarter kcs are
// Bw[0..3] with static indices; the 4 own-quarter MFMAs issue BEFORE the
// partner wait (own h_{t-1} section staged locally at t-1).
//
// Exchange (all R0-proven agent-scope atomics):
//  * producer: bar3 (vmcnt0 drain of all 8 waves' ring stores) + SINGLE
//    release flag store by tid 0. This guarantees data-visible precedes
//    flag-visible by >= the producer's flag-store travel time (~RT/2).
//  * consumer: PIPELINED poll — each iteration issues 3 flag loads AND the
//    3 partner data loads together; when the flags observed in iteration i
//    pass (>= t), the data of iteration i is already the fresh data (see
//    gap argument above; co-issued-load arrival skew << RT/2 margin).
//    This removes one full MALL round-trip per timestep vs poll-then-load.
//    No s_sleep in the hot loop: 16 blocks, poll self-paces at ~1 RT.
__global__ __launch_bounds__(512, 1) void rnn_quad_kernel(
    const _Float16* __restrict__ Whh,
    const _Float16* __restrict__ xwf,
    _Float16* __restrict__ hA,          // [t][g][kc][lane][8] A-frag dump (by q0)
    u64* __restrict__ ring,             // [(g*4+q)][slot][512]
    int* __restrict__ flags)            // [(g*4+q)*64]
{
  const int bidx = blockIdx.x, g = bidx & 3, q = bidx >> 2;
  const int tid = threadIdx.x, lane = tid & 63, wv = tid >> 6;
  const int l15 = lane & 15, quad = lane >> 4;
  const int n0 = q * 128 + wv * 16;

  __shared__ _Float16 alds[16 * 512];
  u64* aldsu = (u64*)alds;

  // 64 weight VGPRs/wave, rotated: Bw[i] holds kc=(q*4+i)&15.
  u32x4 Bw[16];
#pragma unroll
  for (int i = 0; i < 16; ++i) {
    const int kc = (q * 4 + i) & 15;
    Bw[i] = *(const u32x4*)&Whh[(size_t)(n0 + l15) * 512 + kc * 32 + quad * 8];
  }
#pragma unroll
  for (int i = 0; i < 16; ++i)
    asm volatile("" : "+v"(Bw[i]));

  int* pflag[3];
  u64* pring[3];
  int pquar[3];
  {
    int pi = 0;
    for (int qq = 0; qq < 4; ++qq)
      if (qq != q) {
        pflag[pi] = flags + (g * 4 + qq) * 64;
        pring[pi] = ring + (size_t)(g * 4 + qq) * 4 * 512;
        pquar[pi] = qq;
        ++pi;
      }
  }
  int* myflag = flags + (g * 4 + q) * 64;
  u64* myring = ring + (size_t)(g * 4 + q) * 4 * 512;

  const _Float16* xwb = xwf + (size_t)(n0 + l15) * 64 + g * 16 + quad * 4;
  u32x2 pfx = *(const u32x2*)xwb;

  for (int t = 0; t < T_SEQ; ++t) {
    f32x4 acc;
    acc[0] = (float)u2h((unsigned short)(pfx.x & 0xFFFFu));
    acc[1] = (float)u2h((unsigned short)(pfx.x >> 16));
    acc[2] = (float)u2h((unsigned short)(pfx.y & 0xFFFFu));
    acc[3] = (float)u2h((unsigned short)(pfx.y >> 16));
    if (t + 1 < T_SEQ) pfx = *(const u32x2*)(xwb + (size_t)(t + 1) * 32768);

    if (t > 0) {
      // own-quarter kcs first: own alds section staged at t-1, still valid
      // (overwritten only at stage(t), after bar1(t)).
#pragma unroll
      for (int i = 0; i < 4; ++i) {
        const int kc = q * 4 + i;
        f16x8 a = *(const f16x8*)&alds[kc * 512 + lane * 8];
        acc = __builtin_amdgcn_mfma_f32_16x16x32_f16(
            a, __builtin_bit_cast(f16x8, Bw[i]), acc, 0, 0, 0);
      }

      // pipelined flag+data poll (one MALL RT instead of two)
      const int slot = (t - 1) & 3;
      u64 v0, v1, v2;
      {
        int f0, f1, f2;
        do {
          f0 = __hip_atomic_load(pflag[0], __ATOMIC_RELAXED, __HIP_MEMORY_SCOPE_AGENT);
          f1 = __hip_atomic_load(pflag[1], __ATOMIC_RELAXED, __HIP_MEMORY_SCOPE_AGENT);
          f2 = __hip_atomic_load(pflag[2], __ATOMIC_RELAXED, __HIP_MEMORY_SCOPE_AGENT);
          v0 = __hip_atomic_load(pring[0] + (size_t)slot * 512 + tid,
                                 __ATOMIC_RELAXED, __HIP_MEMORY_SCOPE_AGENT);
          v1 = __hip_atomic_load(pring[1] + (size_t)slot * 512 + tid,
                                 __ATOMIC_RELAXED, __HIP_MEMORY_SCOPE_AGENT);
          v2 = __hip_atomic_load(pring[2] + (size_t)slot * 512 + tid,
                                 __ATOMIC_RELAXED, __HIP_MEMORY_SCOPE_AGENT);
        } while ((f0 < t) | (f1 < t) | (f2 < t));
        __builtin_amdgcn_fence(__ATOMIC_ACQUIRE, "agent");
      }
      aldsu[pquar[0] * 512 + tid] = v0;
      aldsu[pquar[1] * 512 + tid] = v1;
      aldsu[pquar[2] * 512 + tid] = v2;
      __syncthreads();  // bar_A: alds(t-1) complete

      if (q == 0) {     // dump h_{t-1} fragplane (16 KB) for xw1/logits/hlast
        u64* dst = (u64*)hA + ((size_t)(t - 1) * 4 + g) * 2048;
#pragma unroll
        for (int i = 0; i < 4; ++i)
          dst[tid + 512 * i] = aldsu[tid + 512 * i];
      }

      // partner kcs in rotated order (static Bw index).
#pragma unroll
      for (int i = 4; i < 16; ++i) {
        const int kc = (q * 4 + i) & 15;
        f16x8 a = *(const f16x8*)&alds[kc * 512 + lane * 8];
        acc = __builtin_amdgcn_mfma_f32_16x16x32_f16(
            a, __builtin_bit_cast(f16x8, Bw[i]), acc, 0, 0, 0);
      }
      __syncthreads();  // bar1: alds reads done before overwrite
    }

    // tanh + stage own cols of h_t into alds in A-frag order
    {
      const int n = n0 + l15;
      const int kc = n >> 5, qd = (n >> 3) & 3, j = n & 7;
#pragma unroll
      for (int r = 0; r < 4; ++r)
        alds[kc * 512 + (qd * 16 + quad * 4 + r) * 8 + j] = (_Float16)fast_tanh(acc[r]);
    }
    __syncthreads();    // bar2: staging visible
    {
      u64 v = aldsu[q * 512 + tid];
      __hip_atomic_store(myring + (size_t)(t & 3) * 512 + tid, v,
                         __ATOMIC_RELAXED, __HIP_MEMORY_SCOPE_AGENT);
    }
    __syncthreads();    // bar3: all waves' ring stores ACKed (per-wave vmcnt0)
    if (tid == 0)
      __hip_atomic_store(myflag, t + 1, __ATOMIC_RELEASE, __HIP_MEMORY_SCOPE_AGENT);
  }

  // epilogue: q0 assembles and dumps h_{T-1}
  if (q == 0) {
    while ((__hip_atomic_load(pflag[0], __ATOMIC_RELAXED, __HIP_MEMORY_SCOPE_AGENT) < T_SEQ) |
           (__hip_atomic_load(pflag[1], __ATOMIC_RELAXED, __HIP_MEMORY_SCOPE_AGENT) < T_SEQ) |
           (__hip_atomic_load(pflag[2], __ATOMIC_RELAXED, __HIP_MEMORY_SCOPE_AGENT) < T_SEQ))
      __builtin_amdgcn_s_sleep(1);
    __builtin_amdgcn_fence(__ATOMIC_ACQUIRE, "agent");
    const int slot = (T_SEQ - 1) & 3;
#pragma unroll
    for (int p = 0; p < 3; ++p) {
      u64 v = __hip_atomic_load(pring[p] + (size_t)slot * 512 + tid,
                                __ATOMIC_RELAXED, __HIP_MEMORY_SCOPE_AGENT);
      aldsu[pquar[p] * 512 + tid] = v;
    }
    __syncthreads();
    u64* dst = (u64*)hA + ((size_t)(T_SEQ - 1) * 4 + g) * 2048;
#pragma unroll
    for (int i = 0; i < 4; ++i)
      dst[tid + 512 * i] = aldsu[tid + 512 * i];
  }
}

// logits[b][t][v] = h1[t,b][:] . Why[v][:] + by[v]; h1 in A-frag layout. Grid 512 x 256.
__global__ __launch_bounds__(256) void logits_kernel(
    const _Float16* __restrict__ h1A, const _Float16* __restrict__ Why,
    const float* __restrict__ by, float* __restrict__ out) {
  const int t = blockIdx.x;
  const int wv = threadIdx.x >> 6, lane = threadIdx.x & 63;
  const int l15 = lane & 15, quad = lane >> 4, bb = wv * 16;
  f32x4 acc[8];
#pragma unroll
  for (int vt = 0; vt < 8; ++vt) { float bv = by[vt * 16 + l15]; acc[vt] = {bv, bv, bv, bv}; }
#pragma unroll
  for (int kc = 0; kc < 16; ++kc) {
    f16x8 a = *(const f16x8*)&h1A[(((size_t)t * 4 + wv) * 16 + kc) * 512 + lane * 8];
#pragma unroll
    for (int vt = 0; vt < 8; ++vt) {
      f16x8 b = *(const f16x8*)&Why[(size_t)(vt * 16 + l15) * 512 + kc * 32 + quad * 8];
      acc[vt] = __builtin_amdgcn_mfma_f32_16x16x32_f16(a, b, acc[vt], 0, 0, 0);
    }
  }
#pragma unroll
  for (int vt = 0; vt < 8; ++vt)
#pragma unroll
    for (int r = 0; r < 4; ++r)
      out[((size_t)(bb + quad * 4 + r) * 512 + t) * 128 + vt * 16 + l15] = acc[vt][r];
}

// h_last from A-frag dumps at t=511. One element each per layer.
__global__ void hlast_kernel(const _Float16* __restrict__ h0A,
                             const _Float16* __restrict__ h1A,
                             float* __restrict__ out) {
  const size_t LOG = (size_t)BATCH * T_SEQ * VOC;
  const size_t HL = (size_t)BATCH * HID;
  int tid = blockIdx.x * 256 + threadIdx.x;
  if (tid < (int)HL) {
    const int b = tid >> 9, n = tid & 511;
    const int gg = b >> 4, m = b & 15;
    const int kc = n >> 5, qd = (n >> 3) & 3, j = n & 7;
    const size_t idx = (((size_t)(T_SEQ - 1) * 4 + gg) * 16 + kc) * 512 + (qd * 16 + m) * 8 + j;
    out[LOG + tid]      = (float)h0A[idx];
    out[LOG + HL + tid] = (float)h1A[idx];
  }
}

extern "C" void kernel_launch(void* const* d_in, const int* in_sizes, int n_in,
                              void* d_out, int out_size, void* d_ws, size_t ws_size,
                              hipStream_t stream) {
  const int* x = (const int*)d_in[0];
  float* out = (float*)d_out;
  char* ws = (char*)d_ws;
  int* flags = (int*)(ws + OFF_FLAGS);
  u64* ring = (u64*)(ws + OFF_RING);      // 2 layers x 32768 u64
  _Float16* arena = (_Float16*)(ws + OFF_ARENA);
  _Float16* xw0f = (_Float16*)(ws + OFF_XW0);
  _Float16* xw1f = (_Float16*)(ws + OFF_XW1);
  _Float16* h0A  = (_Float16*)(ws + OFF_H0A);
  _Float16* h1A  = (_Float16*)(ws + OFF_H1A);

  canon_kernel<<<512, 256, 0, stream>>>(
      (const float*)d_in[1], (const float*)d_in[2], (const float*)d_in[3],
      (const float*)d_in[5], (const float*)d_in[6], (const float*)d_in[8],
      arena, flags);

  xw0_kernel<<<dim3(512, 8), 256, 0, stream>>>(
      x, arena + AOFF_EMB, arena + AOFF_WXH0, (const float*)d_in[4], xw0f);

  rnn_quad_kernel<<<16, 512, 0, stream>>>(
      arena + AOFF_WHH0, xw0f, h0A, ring, flags);

  xw1_kernel<<<dim3(512, 16), 256, 0, stream>>>(
      h0A, arena + AOFF_WXH1, (const float*)d_in[7], xw1f);

  rnn_quad_kernel<<<16, 512, 0, stream>>>(
      arena + AOFF_WHH1, xw1f, h1A, ring + 32768, flags + 16 * 64);

  logits_kernel<<<512, 256, 0, stream>>>(
      h1A, arena + AOFF_WHY, (const float*)d_in[9], out);

  hlast_kernel<<<(BATCH * HID + 255) / 256, 256, 0, stream>>>(h0A, h1A, out);
}

// Round 5
// 2052.518 us; speedup vs baseline: 2.0302x; 1.2362x over previous
//
#include <hip/hip_runtime.h>
#include <hip/hip_fp16.h>

typedef _Float16 f16x8 __attribute__((ext_vector_type(8)));
typedef float f32x4 __attribute__((ext_vector_type(4)));
typedef unsigned int u32x4 __attribute__((ext_vector_type(4)));
typedef unsigned int u32x2 __attribute__((ext_vector_type(2)));
typedef unsigned long long u64;

static constexpr int T_SEQ = 512;
static constexpr int BATCH = 64;
static constexpr int HID   = 512;
static constexpr int VOC   = 128;

// ---- fp16 arena element offsets ----
static constexpr int AOFF_EMB  = 0;        // 128*256
static constexpr int AOFF_WXH0 = 32768;    // 512*256
static constexpr int AOFF_WHH0 = 163840;   // 512*512
static constexpr int AOFF_WXH1 = 425984;   // 512*512
static constexpr int AOFF_WHH1 = 688128;   // 512*512
static constexpr int AOFF_WHY  = 950272;   // 128*512
static constexpr int ATOT      = 1015808;

// ---- ws byte offsets ----
// ring: TAGGED 16B entries [data u64][tag u32][0u32].
//   2 layers x 16 regions x 4 slots x 512 tids x 16B = 1 MB.
static constexpr size_t OFF_RING  = 16384;
static constexpr size_t RING_BYTES = 2ull * 16 * 4 * 512 * 16;          // 1 MB
static constexpr int    RING_L_STRIDE = 16 * 4 * 512 * 2;               // u64s per layer
static constexpr size_t OFF_ARENA = 1114112;              // ring ends at 1064960
static constexpr size_t PLANE_B   = (size_t)T_SEQ * BATCH * HID * 2;    // 32 MB
static constexpr size_t OFF_XW0   = 4u << 20;             // arena ends at 3 MB
static constexpr size_t OFF_XW1   = OFF_XW0 + PLANE_B;
static constexpr size_t OFF_H0A   = OFF_XW1 + PLANE_B;    // A-frag layout [t][g][kc][lane][8]
static constexpr size_t OFF_H1A   = OFF_H0A + PLANE_B;    // ends ~132 MB

__device__ __forceinline__ unsigned short h2u(_Float16 h) {
  union { _Float16 h; unsigned short u; } c; c.h = h; return c.u;
}
__device__ __forceinline__ _Float16 u2h(unsigned short u) {
  union { unsigned short u; _Float16 h; } c; c.u = u; return c.h;
}
__device__ __forceinline__ float fast_tanh(float x) {
  float e = __expf(2.0f * x);
  return 1.0f - 2.0f * __builtin_amdgcn_rcpf(e + 1.0f);
}

// ---- tagged 16B message primitives (single-transaction data+tag) ----
// sc0 sc1 = strongest (system) cache policy: bypass L1/L2, visible at MALL.
// Tag rides in the SAME dwordx4 as the data -> no separate ordering needed.
__device__ __forceinline__ void store16_sys(u64* addr, u64 data, unsigned tag) {
  u32x4 v;
  v.x = (unsigned)data; v.y = (unsigned)(data >> 32);
  v.z = tag;            v.w = 0u;
  asm volatile("global_store_dwordx4 %0, %1, off sc0 sc1"
               :: "v"(addr), "v"(v) : "memory");
}
__device__ __forceinline__ void issue3x16(const u64* a, const u64* b, const u64* c,
                                          u32x4& v0, u32x4& v1, u32x4& v2) {
  asm volatile("global_load_dwordx4 %0, %3, off sc0 sc1\n\t"
               "global_load_dwordx4 %1, %4, off sc0 sc1\n\t"
               "global_load_dwordx4 %2, %5, off sc0 sc1"
               : "=&v"(v0), "=&v"(v1), "=&v"(v2)
               : "v"(a), "v"(b), "v"(c)
               : "memory");
}
__device__ __forceinline__ void wait3(u32x4& v0, u32x4& v1, u32x4& v2) {
  asm volatile("s_waitcnt vmcnt(0)" : "+v"(v0), "+v"(v1), "+v"(v2) :: "memory");
}
__device__ __forceinline__ void load3x16_sys(const u64* a, const u64* b, const u64* c,
                                             u32x4& v0, u32x4& v1, u32x4& v2) {
  asm volatile("global_load_dwordx4 %0, %3, off sc0 sc1\n\t"
               "global_load_dwordx4 %1, %4, off sc0 sc1\n\t"
               "global_load_dwordx4 %2, %5, off sc0 sc1\n\t"
               "s_waitcnt vmcnt(0)"
               : "=&v"(v0), "=&v"(v1), "=&v"(v2)
               : "v"(a), "v"(b), "v"(c)
               : "memory");
}

// fp32 params -> fp16 arena; zero the tagged ring (262144 ints = 1 MB).
__global__ __launch_bounds__(256) void canon_kernel(
    const float* p0, const float* p1, const float* p2, const float* p3,
    const float* p4, const float* p5, _Float16* __restrict__ dst,
    int* __restrict__ ringz) {
  for (int i = blockIdx.x * 256 + threadIdx.x; i < (int)(RING_BYTES / 4);
       i += gridDim.x * 256)
    ringz[i] = 0;
  const float* srcs[6] = {p0, p1, p2, p3, p4, p5};
  const int ns[6] = {32768, 131072, 262144, 262144, 262144, 65536};
  for (int i = blockIdx.x * 256 + threadIdx.x; i < ATOT; i += gridDim.x * 256) {
    int off = i, s = 0;
    while (off >= ns[s]) { off -= ns[s]; ++s; }
    dst[i] = (_Float16)srcs[s][off];
  }
}

// xwf0[t][n][b] = emb[x[b,t]][:] . Wxh0[n][:] + bh0[n].  Grid (512, 8) x 256.
__global__ __launch_bounds__(256) void xw0_kernel(
    const int* __restrict__ x, const _Float16* __restrict__ emb,
    const _Float16* __restrict__ Wxh, const float* __restrict__ bh,
    _Float16* __restrict__ xwf) {
  __shared__ _Float16 Bs[64][264];
  const int t = blockIdx.x, n0 = blockIdx.y * 64, tid = threadIdx.x;
#pragma unroll
  for (int rep = 0; rep < 8; ++rep) {
    int flat = rep * 256 + tid;
    int row = flat >> 5, c8 = flat & 31;
    *(f16x8*)&Bs[row][c8 * 8] = *(const f16x8*)&Wxh[(size_t)(n0 + row) * 256 + c8 * 8];
  }
  __syncthreads();
  const int wv = tid >> 6, lane = tid & 63, l15 = lane & 15, quad = lane >> 4;
  const int b = wv * 16 + l15;
  const int idx = x[b * 512 + t];
  f32x4 acc[4];
#pragma unroll
  for (int nt = 0; nt < 4; ++nt) { float bv = bh[n0 + nt * 16 + l15]; acc[nt] = {bv, bv, bv, bv}; }
#pragma unroll
  for (int kc = 0; kc < 8; ++kc) {
    f16x8 a = *(const f16x8*)&emb[(size_t)idx * 256 + kc * 32 + quad * 8];
#pragma unroll
    for (int nt = 0; nt < 4; ++nt) {
      f16x8 bf = *(const f16x8*)&Bs[nt * 16 + l15][kc * 32 + quad * 8];
      acc[nt] = __builtin_amdgcn_mfma_f32_16x16x32_f16(a, bf, acc[nt], 0, 0, 0);
    }
  }
#pragma unroll
  for (int nt = 0; nt < 4; ++nt) {
    unsigned int lo = (unsigned int)h2u((_Float16)acc[nt][0]) |
                      ((unsigned int)h2u((_Float16)acc[nt][1]) << 16);
    unsigned int hi = (unsigned int)h2u((_Float16)acc[nt][2]) |
                      ((unsigned int)h2u((_Float16)acc[nt][3]) << 16);
    u32x2 pk = {lo, hi};
    *(u32x2*)&xwf[(size_t)t * 32768 + (size_t)(n0 + nt * 16 + l15) * 64 + wv * 16 + quad * 4] = pk;
  }
}

// xwf1[t][n][b] = h0[t,b][:] . Wxh1[n][:] + bh1[n]; h0 read in A-frag layout.
// Grid (512, 16) x 256.
__global__ __launch_bounds__(256) void xw1_kernel(
    const _Float16* __restrict__ h0A, const _Float16* __restrict__ Wxh,
    const float* __restrict__ bh, _Float16* __restrict__ xwf) {
  __shared__ _Float16 Bs[32][520];
  const int t = blockIdx.x, n0 = blockIdx.y * 32, tid = threadIdx.x;
#pragma unroll
  for (int rep = 0; rep < 8; ++rep) {
    int flat = rep * 256 + tid;
    int row = flat >> 6, c8 = flat & 63;
    *(f16x8*)&Bs[row][c8 * 8] = *(const f16x8*)&Wxh[(size_t)(n0 + row) * 512 + c8 * 8];
  }
  __syncthreads();
  const int wv = tid >> 6, lane = tid & 63, l15 = lane & 15, quad = lane >> 4;
  f32x4 acc[2];
#pragma unroll
  for (int nt = 0; nt < 2; ++nt) { float bv = bh[n0 + nt * 16 + l15]; acc[nt] = {bv, bv, bv, bv}; }
#pragma unroll
  for (int kc = 0; kc < 16; ++kc) {
    f16x8 a = *(const f16x8*)&h0A[(((size_t)t * 4 + wv) * 16 + kc) * 512 + lane * 8];
#pragma unroll
    for (int nt = 0; nt < 2; ++nt) {
      f16x8 bf = *(const f16x8*)&Bs[nt * 16 + l15][kc * 32 + quad * 8];
      acc[nt] = __builtin_amdgcn_mfma_f32_16x16x32_f16(a, bf, acc[nt], 0, 0, 0);
    }
  }
#pragma unroll
  for (int nt = 0; nt < 2; ++nt) {
    unsigned int lo = (unsigned int)h2u((_Float16)acc[nt][0]) |
                      ((unsigned int)h2u((_Float16)acc[nt][1]) << 16);
    unsigned int hi = (unsigned int)h2u((_Float16)acc[nt][2]) |
                      ((unsigned int)h2u((_Float16)acc[nt][3]) << 16);
    u32x2 pk = {lo, hi};
    *(u32x2*)&xwf[(size_t)t * 32768 + (size_t)(n0 + nt * 16 + l15) * 64 + wv * 16 + quad * 4] = pk;
  }
}

// Quad recurrence: grid 16 x 512. Block b: group g=b&3, quarter q=b>>2.
// Exchange via TAGGED 16B ring messages (data u64 + tag u32 in ONE dwordx4):
//  * producer (after bar2): each thread stores its own (h-data, tag=t+1) -> no
//    bar3, no flag, no store-ACK drain on the critical path. Publication is
//    per-THREAD, so the consumer is not gated by the producer's slowest wave.
//  * consumer: polls the 3 partner entries directly (dwordx4 sc0 sc1, tag==t
//    exact match). First poll issued BEFORE the 4 own-quarter MFMAs so its
//    latency hides under them. Exact match is stale-proof across replays
//    (stale tags are == t mod 4 but > t; canon re-zeroes the ring anyway).
//  * atomicity: tag+data share one aligned 16B store = one L2/MALL
//    transaction; no tear window.
__global__ __launch_bounds__(512, 1) void rnn_quad_kernel(
    const _Float16* __restrict__ Whh,
    const _Float16* __restrict__ xwf,
    _Float16* __restrict__ hA,          // [t][g][kc][lane][8] A-frag dump (by q0)
    u64* __restrict__ ring)             // [(g*4+q)][slot][512] x 16B entries
{
  const int bidx = blockIdx.x, g = bidx & 3, q = bidx >> 2;
  const int tid = threadIdx.x, lane = tid & 63, wv = tid >> 6;
  const int l15 = lane & 15, quad = lane >> 4;
  const int n0 = q * 128 + wv * 16;

  __shared__ _Float16 alds[16 * 512];
  u64* aldsu = (u64*)alds;

  // 64 weight VGPRs/wave, rotated: Bw[i] holds kc=(q*4+i)&15.
  u32x4 Bw[16];
#pragma unroll
  for (int i = 0; i < 16; ++i) {
    const int kc = (q * 4 + i) & 15;
    Bw[i] = *(const u32x4*)&Whh[(size_t)(n0 + l15) * 512 + kc * 32 + quad * 8];
  }
#pragma unroll
  for (int i = 0; i < 16; ++i)
    asm volatile("" : "+v"(Bw[i]));

  // region stride = 4 slots * 512 tids * 2 u64 = 4096 u64
  u64* pring[3];
  int pquar[3];
  {
    int pi = 0;
    for (int qq = 0; qq < 4; ++qq)
      if (qq != q) {
        pring[pi] = ring + (size_t)(g * 4 + qq) * 4096;
        pquar[pi] = qq;
        ++pi;
      }
  }
  u64* myring = ring + (size_t)(g * 4 + q) * 4096;

  const _Float16* xwb = xwf + (size_t)(n0 + l15) * 64 + g * 16 + quad * 4;
  u32x2 pfx = *(const u32x2*)xwb;

  for (int t = 0; t < T_SEQ; ++t) {
    f32x4 acc;
    acc[0] = (float)u2h((unsigned short)(pfx.x & 0xFFFFu));
    acc[1] = (float)u2h((unsigned short)(pfx.x >> 16));
    acc[2] = (float)u2h((unsigned short)(pfx.y & 0xFFFFu));
    acc[3] = (float)u2h((unsigned short)(pfx.y >> 16));
    if (t + 1 < T_SEQ) pfx = *(const u32x2*)(xwb + (size_t)(t + 1) * 32768);

    if (t > 0) {
      const int slot = (t - 1) & 3;
      const u64* a0 = pring[0] + (size_t)slot * 1024 + tid * 2;
      const u64* a1 = pring[1] + (size_t)slot * 1024 + tid * 2;
      const u64* a2 = pring[2] + (size_t)slot * 1024 + tid * 2;
      u32x4 r0, r1, r2;
      issue3x16(a0, a1, a2, r0, r1, r2);   // poll #1 in flight under own MFMAs

      // own-quarter kcs: own alds section staged at t-1, still valid.
#pragma unroll
      for (int i = 0; i < 4; ++i) {
        const int kc = q * 4 + i;
        f16x8 a = *(const f16x8*)&alds[kc * 512 + lane * 8];
        acc = __builtin_amdgcn_mfma_f32_16x16x32_f16(
            a, __builtin_bit_cast(f16x8, Bw[i]), acc, 0, 0, 0);
      }

      wait3(r0, r1, r2);
      const unsigned wtag = (unsigned)t;
      while ((r0.z != wtag) | (r1.z != wtag) | (r2.z != wtag))
        load3x16_sys(a0, a1, a2, r0, r1, r2);

      aldsu[pquar[0] * 512 + tid] = ((u64)r0.y << 32) | r0.x;
      aldsu[pquar[1] * 512 + tid] = ((u64)r1.y << 32) | r1.x;
      aldsu[pquar[2] * 512 + tid] = ((u64)r2.y << 32) | r2.x;
      __syncthreads();  // bar_A: alds(t-1) complete

      if (q == 0) {     // dump h_{t-1} fragplane (16 KB) for xw1/logits/hlast
        u64* dst = (u64*)hA + ((size_t)(t - 1) * 4 + g) * 2048;
#pragma unroll
        for (int i = 0; i < 4; ++i)
          dst[tid + 512 * i] = aldsu[tid + 512 * i];
      }

      // partner kcs in rotated order (static Bw index).
#pragma unroll
      for (int i = 4; i < 16; ++i) {
        const int kc = (q * 4 + i) & 15;
        f16x8 a = *(const f16x8*)&alds[kc * 512 + lane * 8];
        acc = __builtin_amdgcn_mfma_f32_16x16x32_f16(
            a, __builtin_bit_cast(f16x8, Bw[i]), acc, 0, 0, 0);
      }
      __syncthreads();  // bar1: alds reads done before overwrite
    }

    // tanh + stage own cols of h_t into alds in A-frag order
    {
      const int n = n0 + l15;
      const int kc = n >> 5, qd = (n >> 3) & 3, j = n & 7;
#pragma unroll
      for (int r = 0; r < 4; ++r)
        alds[kc * 512 + (qd * 16 + quad * 4 + r) * 8 + j] = (_Float16)fast_tanh(acc[r]);
    }
    __syncthreads();    // bar2: staging visible (also: all alds reads of t-1 done)
    {
      // per-thread tagged publish; no bar3, no flag.
      u64 v = aldsu[q * 512 + tid];
      store16_sys(myring + (size_t)(t & 3) * 1024 + tid * 2, v, (unsigned)(t + 1));
    }
  }

  // epilogue: q0 assembles and dumps h_{T-1}
  if (q == 0) {
    const int slot = (T_SEQ - 1) & 3;
    const u64* a0 = pring[0] + (size_t)slot * 1024 + tid * 2;
    const u64* a1 = pring[1] + (size_t)slot * 1024 + tid * 2;
    const u64* a2 = pring[2] + (size_t)slot * 1024 + tid * 2;
    u32x4 r0, r1, r2;
    load3x16_sys(a0, a1, a2, r0, r1, r2);
    const unsigned wtag = (unsigned)T_SEQ;
    while ((r0.z != wtag) | (r1.z != wtag) | (r2.z != wtag))
      load3x16_sys(a0, a1, a2, r0, r1, r2);
    aldsu[pquar[0] * 512 + tid] = ((u64)r0.y << 32) | r0.x;
    aldsu[pquar[1] * 512 + tid] = ((u64)r1.y << 32) | r1.x;
    aldsu[pquar[2] * 512 + tid] = ((u64)r2.y << 32) | r2.x;
    __syncthreads();
    u64* dst = (u64*)hA + ((size_t)(T_SEQ - 1) * 4 + g) * 2048;
#pragma unroll
    for (int i = 0; i < 4; ++i)
      dst[tid + 512 * i] = aldsu[tid + 512 * i];
  }
}

// logits[b][t][v] = h1[t,b][:] . Why[v][:] + by[v]; h1 in A-frag layout. Grid 512 x 256.
__global__ __launch_bounds__(256) void logits_kernel(
    const _Float16* __restrict__ h1A, const _Float16* __restrict__ Why,
    const float* __restrict__ by, float* __restrict__ out) {
  const int t = blockIdx.x;
  const int wv = threadIdx.x >> 6, lane = threadIdx.x & 63;
  const int l15 = lane & 15, quad = lane >> 4, bb = wv * 16;
  f32x4 acc[8];
#pragma unroll
  for (int vt = 0; vt < 8; ++vt) { float bv = by[vt * 16 + l15]; acc[vt] = {bv, bv, bv, bv}; }
#pragma unroll
  for (int kc = 0; kc < 16; ++kc) {
    f16x8 a = *(const f16x8*)&h1A[(((size_t)t * 4 + wv) * 16 + kc) * 512 + lane * 8];
#pragma unroll
    for (int vt = 0; vt < 8; ++vt) {
      f16x8 b = *(const f16x8*)&Why[(size_t)(vt * 16 + l15) * 512 + kc * 32 + quad * 8];
      acc[vt] = __builtin_amdgcn_mfma_f32_16x16x32_f16(a, b, acc[vt], 0, 0, 0);
    }
  }
#pragma unroll
  for (int vt = 0; vt < 8; ++vt)
#pragma unroll
    for (int r = 0; r < 4; ++r)
      out[((size_t)(bb + quad * 4 + r) * 512 + t) * 128 + vt * 16 + l15] = acc[vt][r];
}

// h_last from A-frag dumps at t=511. One element each per layer.
__global__ void hlast_kernel(const _Float16* __restrict__ h0A,
                             const _Float16* __restrict__ h1A,
                             float* __restrict__ out) {
  const size_t LOG = (size_t)BATCH * T_SEQ * VOC;
  const size_t HL = (size_t)BATCH * HID;
  int tid = blockIdx.x * 256 + threadIdx.x;
  if (tid < (int)HL) {
    const int b = tid >> 9, n = tid & 511;
    const int gg = b >> 4, m = b & 15;
    const int kc = n >> 5, qd = (n >> 3) & 3, j = n & 7;
    const size_t idx = (((size_t)(T_SEQ - 1) * 4 + gg) * 16 + kc) * 512 + (qd * 16 + m) * 8 + j;
    out[LOG + tid]      = (float)h0A[idx];
    out[LOG + HL + tid] = (float)h1A[idx];
  }
}

extern "C" void kernel_launch(void* const* d_in, const int* in_sizes, int n_in,
                              void* d_out, int out_size, void* d_ws, size_t ws_size,
                              hipStream_t stream) {
  const int* x = (const int*)d_in[0];
  float* out = (float*)d_out;
  char* ws = (char*)d_ws;
  u64* ring = (u64*)(ws + OFF_RING);      // 2 layers x 65536 u64 (16B entries)
  _Float16* arena = (_Float16*)(ws + OFF_ARENA);
  _Float16* xw0f = (_Float16*)(ws + OFF_XW0);
  _Float16* xw1f = (_Float16*)(ws + OFF_XW1);
  _Float16* h0A  = (_Float16*)(ws + OFF_H0A);
  _Float16* h1A  = (_Float16*)(ws + OFF_H1A);

  canon_kernel<<<512, 256, 0, stream>>>(
      (const float*)d_in[1], (const float*)d_in[2], (const float*)d_in[3],
      (const float*)d_in[5], (const float*)d_in[6], (const float*)d_in[8],
      arena, (int*)ring);

  xw0_kernel<<<dim3(512, 8), 256, 0, stream>>>(
      x, arena + AOFF_EMB, arena + AOFF_WXH0, (const float*)d_in[4], xw0f);

  rnn_quad_kernel<<<16, 512, 0, stream>>>(
      arena + AOFF_WHH0, xw0f, h0A, ring);

  xw1_kernel<<<dim3(512, 16), 256, 0, stream>>>(
      h0A, arena + AOFF_WXH1, (const float*)d_in[7], xw1f);

  rnn_quad_kernel<<<16, 512, 0, stream>>>(
      arena + AOFF_WHH1, xw1f, h1A, ring + RING_L_STRIDE);

  logits_kernel<<<512, 256, 0, stream>>>(
      h1A, arena + AOFF_WHY, (const float*)d_in[9], out);

  hlast_kernel<<<(BATCH * HID + 255) / 256, 256, 0, stream>>>(h0A, h1A, out);
}

// Round 6
// 1278.667 us; speedup vs baseline: 3.2589x; 1.6052x over previous
//
#include <hip/hip_runtime.h>
#include <hip/hip_fp16.h>

typedef _Float16 f16x8 __attribute__((ext_vector_type(8)));
typedef float f32x4 __attribute__((ext_vector_type(4)));
typedef unsigned int u32x4 __attribute__((ext_vector_type(4)));
typedef unsigned int u32x2 __attribute__((ext_vector_type(2)));
typedef unsigned long long u64;

static constexpr int T_SEQ = 512;
static constexpr int BATCH = 64;
static constexpr int HID   = 512;
static constexpr int VOC   = 128;

// ---- fp16 arena element offsets ----
static constexpr int AOFF_EMB  = 0;        // 128*256
static constexpr int AOFF_WXH0 = 32768;    // 512*256
static constexpr int AOFF_WHH0 = 163840;   // 512*512
static constexpr int AOFF_WXH1 = 425984;   // 512*512
static constexpr int AOFF_WHH1 = 688128;   // 512*512
static constexpr int AOFF_WHY  = 950272;   // 128*512
static constexpr int ATOT      = 1015808;

// ---- ws byte offsets (repacked; total 137,314,304 <= proven 138,412,032) ----
// ring: tagged 16B entries, 32 regions (16 layer0 + 16 layer1) x 4 slots x 512.
static constexpr size_t OFF_RING   = 16384;
static constexpr size_t RING_BYTES = 32ull * 4 * 512 * 16;            // 1 MB
// hist: full-length tagged h0 history [t][g][q][tid] 16B entries = 64 MB.
static constexpr size_t OFF_HIST   = OFF_RING + RING_BYTES;           // 1,064,960
static constexpr size_t HIST_BYTES = 512ull * 16 * 512 * 16;          // 67,108,864
static constexpr size_t OFF_ARENA  = OFF_HIST + HIST_BYTES;           // 68,173,824
static constexpr size_t OFF_XW0    = OFF_ARENA + 2ull * ATOT;         // 70,205,440
static constexpr size_t PLANE_B    = (size_t)T_SEQ * BATCH * HID * 2; // 32 MB
static constexpr size_t OFF_H1A    = OFF_XW0 + PLANE_B;               // 103,759,872

__device__ __forceinline__ unsigned short h2u(_Float16 h) {
  union { _Float16 h; unsigned short u; } c; c.h = h; return c.u;
}
__device__ __forceinline__ _Float16 u2h(unsigned short u) {
  union { unsigned short u; _Float16 h; } c; c.u = u; return c.h;
}
__device__ __forceinline__ float fast_tanh(float x) {
  float e = __expf(2.0f * x);
  return 1.0f - 2.0f * __builtin_amdgcn_rcpf(e + 1.0f);
}

// ---- tagged 16B message primitives (single-transaction data+tag) ----
__device__ __forceinline__ void store16_sys(u64* addr, u64 data, unsigned tag) {
  u32x4 v;
  v.x = (unsigned)data; v.y = (unsigned)(data >> 32);
  v.z = tag;            v.w = 0u;
  asm volatile("global_store_dwordx4 %0, %1, off sc0 sc1"
               :: "v"(addr), "v"(v) : "memory");
}
__device__ __forceinline__ void issue3x16(const u64* a, const u64* b, const u64* c,
                                          u32x4& v0, u32x4& v1, u32x4& v2) {
  asm volatile("global_load_dwordx4 %0, %3, off sc0 sc1\n\t"
               "global_load_dwordx4 %1, %4, off sc0 sc1\n\t"
               "global_load_dwordx4 %2, %5, off sc0 sc1"
               : "=&v"(v0), "=&v"(v1), "=&v"(v2)
               : "v"(a), "v"(b), "v"(c)
               : "memory");
}
__device__ __forceinline__ void issue4x16(const u64* a, const u64* b, const u64* c,
                                          const u64* d, u32x4& v0, u32x4& v1,
                                          u32x4& v2, u32x4& v3) {
  asm volatile("global_load_dwordx4 %0, %4, off sc0 sc1\n\t"
               "global_load_dwordx4 %1, %5, off sc0 sc1\n\t"
               "global_load_dwordx4 %2, %6, off sc0 sc1\n\t"
               "global_load_dwordx4 %3, %7, off sc0 sc1"
               : "=&v"(v0), "=&v"(v1), "=&v"(v2), "=&v"(v3)
               : "v"(a), "v"(b), "v"(c), "v"(d)
               : "memory");
}
__device__ __forceinline__ void wait3(u32x4& v0, u32x4& v1, u32x4& v2) {
  asm volatile("s_waitcnt vmcnt(0)" : "+v"(v0), "+v"(v1), "+v"(v2) :: "memory");
}
__device__ __forceinline__ void wait4_v3(u32x4& v0, u32x4& v1, u32x4& v2, u32x4& v3) {
  // waits until <=3 outstanding: the 4 hist loads (issued first) are done.
  asm volatile("s_waitcnt vmcnt(3)" : "+v"(v0), "+v"(v1), "+v"(v2), "+v"(v3) :: "memory");
}
__device__ __forceinline__ void wait4_v0(u32x4& v0, u32x4& v1, u32x4& v2, u32x4& v3) {
  asm volatile("s_waitcnt vmcnt(0)" : "+v"(v0), "+v"(v1), "+v"(v2), "+v"(v3) :: "memory");
}
__device__ __forceinline__ void load3x16_sys(const u64* a, const u64* b, const u64* c,
                                             u32x4& v0, u32x4& v1, u32x4& v2) {
  asm volatile("global_load_dwordx4 %0, %3, off sc0 sc1\n\t"
               "global_load_dwordx4 %1, %4, off sc0 sc1\n\t"
               "global_load_dwordx4 %2, %5, off sc0 sc1\n\t"
               "s_waitcnt vmcnt(0)"
               : "=&v"(v0), "=&v"(v1), "=&v"(v2)
               : "v"(a), "v"(b), "v"(c)
               : "memory");
}
__device__ __forceinline__ void load4x16_sys(const u64* a, const u64* b, const u64* c,
                                             const u64* d, u32x4& v0, u32x4& v1,
                                             u32x4& v2, u32x4& v3) {
  asm volatile("global_load_dwordx4 %0, %4, off sc0 sc1\n\t"
               "global_load_dwordx4 %1, %5, off sc0 sc1\n\t"
               "global_load_dwordx4 %2, %6, off sc0 sc1\n\t"
               "global_load_dwordx4 %3, %7, off sc0 sc1\n\t"
               "s_waitcnt vmcnt(0)"
               : "=&v"(v0), "=&v"(v1), "=&v"(v2), "=&v"(v3)
               : "v"(a), "v"(b), "v"(c), "v"(d)
               : "memory");
}

// fp32 params -> fp16 arena; zero ring+hist (contiguous, 17,039,360 ints).
__global__ __launch_bounds__(256) void canon_kernel(
    const float* p0, const float* p1, const float* p2, const float* p3,
    const float* p4, const float* p5, _Float16* __restrict__ dst,
    int* __restrict__ ringhist) {
  const int NZ = (int)((RING_BYTES + HIST_BYTES) / 4);
  for (int i = blockIdx.x * 256 + threadIdx.x; i < NZ; i += gridDim.x * 256)
    ringhist[i] = 0;
  const float* srcs[6] = {p0, p1, p2, p3, p4, p5};
  const int ns[6] = {32768, 131072, 262144, 262144, 262144, 65536};
  for (int i = blockIdx.x * 256 + threadIdx.x; i < ATOT; i += gridDim.x * 256) {
    int off = i, s = 0;
    while (off >= ns[s]) { off -= ns[s]; ++s; }
    dst[i] = (_Float16)srcs[s][off];
  }
}

// xwf0[t][n][b] = emb[x[b,t]][:] . Wxh0[n][:] + bh0[n].  Grid (512, 8) x 256.
__global__ __launch_bounds__(256) void xw0_kernel(
    const int* __restrict__ x, const _Float16* __restrict__ emb,
    const _Float16* __restrict__ Wxh, const float* __restrict__ bh,
    _Float16* __restrict__ xwf) {
  __shared__ _Float16 Bs[64][264];
  const int t = blockIdx.x, n0 = blockIdx.y * 64, tid = threadIdx.x;
#pragma unroll
  for (int rep = 0; rep < 8; ++rep) {
    int flat = rep * 256 + tid;
    int row = flat >> 5, c8 = flat & 31;
    *(f16x8*)&Bs[row][c8 * 8] = *(const f16x8*)&Wxh[(size_t)(n0 + row) * 256 + c8 * 8];
  }
  __syncthreads();
  const int wv = tid >> 6, lane = tid & 63, l15 = lane & 15, quad = lane >> 4;
  const int b = wv * 16 + l15;
  const int idx = x[b * 512 + t];
  f32x4 acc[4];
#pragma unroll
  for (int nt = 0; nt < 4; ++nt) { float bv = bh[n0 + nt * 16 + l15]; acc[nt] = {bv, bv, bv, bv}; }
#pragma unroll
  for (int kc = 0; kc < 8; ++kc) {
    f16x8 a = *(const f16x8*)&emb[(size_t)idx * 256 + kc * 32 + quad * 8];
#pragma unroll
    for (int nt = 0; nt < 4; ++nt) {
      f16x8 bf = *(const f16x8*)&Bs[nt * 16 + l15][kc * 32 + quad * 8];
      acc[nt] = __builtin_amdgcn_mfma_f32_16x16x32_f16(a, bf, acc[nt], 0, 0, 0);
    }
  }
#pragma unroll
  for (int nt = 0; nt < 4; ++nt) {
    unsigned int lo = (unsigned int)h2u((_Float16)acc[nt][0]) |
                      ((unsigned int)h2u((_Float16)acc[nt][1]) << 16);
    unsigned int hi = (unsigned int)h2u((_Float16)acc[nt][2]) |
                      ((unsigned int)h2u((_Float16)acc[nt][3]) << 16);
    u32x2 pk = {lo, hi};
    *(u32x2*)&xwf[(size_t)t * 32768 + (size_t)(n0 + nt * 16 + l15) * 64 + wv * 16 + quad * 4] = pk;
  }
}

// ---- layer-0 recurrence (R5-proven loop + per-step hist publish, no hA dump)
__device__ __forceinline__ void layer0_loop(
    const _Float16* __restrict__ Whh, const _Float16* __restrict__ xwf,
    u64* __restrict__ ring, u64* __restrict__ hist,
    _Float16* alds, const int g, const int q, const int tid) {
  u64* aldsu = (u64*)alds;
  const int lane = tid & 63, wv = tid >> 6, l15 = lane & 15, quad = lane >> 4;
  const int n0 = q * 128 + wv * 16;

  u32x4 Bw[16];
#pragma unroll
  for (int i = 0; i < 16; ++i) {
    const int kc = (q * 4 + i) & 15;
    Bw[i] = *(const u32x4*)&Whh[(size_t)(n0 + l15) * 512 + kc * 32 + quad * 8];
  }
#pragma unroll
  for (int i = 0; i < 16; ++i)
    asm volatile("" : "+v"(Bw[i]));

  u64* pring[3];
  int pquar[3];
  {
    int pi = 0;
    for (int qq = 0; qq < 4; ++qq)
      if (qq != q) { pring[pi] = ring + (size_t)(g * 4 + qq) * 4096; pquar[pi] = qq; ++pi; }
  }
  u64* myring = ring + (size_t)(g * 4 + q) * 4096;

  const _Float16* xwb = xwf + (size_t)(n0 + l15) * 64 + g * 16 + quad * 4;
  u32x2 pfx = *(const u32x2*)xwb;

  for (int t = 0; t < T_SEQ; ++t) {
    f32x4 acc;
    acc[0] = (float)u2h((unsigned short)(pfx.x & 0xFFFFu));
    acc[1] = (float)u2h((unsigned short)(pfx.x >> 16));
    acc[2] = (float)u2h((unsigned short)(pfx.y & 0xFFFFu));
    acc[3] = (float)u2h((unsigned short)(pfx.y >> 16));
    if (t + 1 < T_SEQ) pfx = *(const u32x2*)(xwb + (size_t)(t + 1) * 32768);

    if (t > 0) {
      const int slot = (t - 1) & 3;
      const u64* a0 = pring[0] + (size_t)slot * 1024 + tid * 2;
      const u64* a1 = pring[1] + (size_t)slot * 1024 + tid * 2;
      const u64* a2 = pring[2] + (size_t)slot * 1024 + tid * 2;
      u32x4 r0, r1, r2;
      issue3x16(a0, a1, a2, r0, r1, r2);   // poll #1 in flight under own MFMAs

#pragma unroll
      for (int i = 0; i < 4; ++i) {
        const int kc = q * 4 + i;
        f16x8 a = *(const f16x8*)&alds[kc * 512 + lane * 8];
        acc = __builtin_amdgcn_mfma_f32_16x16x32_f16(
            a, __builtin_bit_cast(f16x8, Bw[i]), acc, 0, 0, 0);
      }

      wait3(r0, r1, r2);
      const unsigned wtag = (unsigned)t;
      while ((r0.z != wtag) | (r1.z != wtag) | (r2.z != wtag))
        load3x16_sys(a0, a1, a2, r0, r1, r2);

      aldsu[pquar[0] * 512 + tid] = ((u64)r0.y << 32) | r0.x;
      aldsu[pquar[1] * 512 + tid] = ((u64)r1.y << 32) | r1.x;
      aldsu[pquar[2] * 512 + tid] = ((u64)r2.y << 32) | r2.x;
      __syncthreads();  // bar_A

#pragma unroll
      for (int i = 4; i < 16; ++i) {
        const int kc = (q * 4 + i) & 15;
        f16x8 a = *(const f16x8*)&alds[kc * 512 + lane * 8];
        acc = __builtin_amdgcn_mfma_f32_16x16x32_f16(
            a, __builtin_bit_cast(f16x8, Bw[i]), acc, 0, 0, 0);
      }
      __syncthreads();  // bar1
    }

    {
      const int n = n0 + l15;
      const int kc = n >> 5, qd = (n >> 3) & 3, j = n & 7;
#pragma unroll
      for (int r = 0; r < 4; ++r)
        alds[kc * 512 + (qd * 16 + quad * 4 + r) * 8 + j] = (_Float16)fast_tanh(acc[r]);
    }
    __syncthreads();    // bar2
    {
      u64 v = aldsu[q * 512 + tid];
      store16_sys(myring + (size_t)(t & 3) * 1024 + tid * 2, v, (unsigned)(t + 1));
      store16_sys(hist + ((size_t)(t * 16 + g * 4 + q) * 512 + tid) * 2, v,
                  (unsigned)(t + 1));   // full-history publish for layer 1 + hlast
    }
  }
}

// ---- layer-1 recurrence: fused xw1 (A = h0 from hist) + Whh1 recurrence.
__device__ __forceinline__ void layer1_loop(
    const _Float16* __restrict__ Whh, const _Float16* __restrict__ Wxh,
    const float* __restrict__ bh, const u64* __restrict__ hist,
    u64* __restrict__ ring, _Float16* __restrict__ h1A,
    _Float16* alds, _Float16* xlds, const int g, const int q, const int tid) {
  u64* aldsu = (u64*)alds;
  u64* xldsu = (u64*)xlds;
  const int lane = tid & 63, wv = tid >> 6, l15 = lane & 15, quad = lane >> 4;
  const int n0 = q * 128 + wv * 16;

  u32x4 Bh[16], Bx[16];
#pragma unroll
  for (int i = 0; i < 16; ++i) {
    const int kc = (q * 4 + i) & 15;
    Bh[i] = *(const u32x4*)&Whh[(size_t)(n0 + l15) * 512 + kc * 32 + quad * 8];
  }
#pragma unroll
  for (int i = 0; i < 16; ++i)
    Bx[i] = *(const u32x4*)&Wxh[(size_t)(n0 + l15) * 512 + i * 32 + quad * 8];
#pragma unroll
  for (int i = 0; i < 16; ++i) {
    asm volatile("" : "+v"(Bh[i]));
    asm volatile("" : "+v"(Bx[i]));
  }
  const float bv = bh[n0 + l15];

  u64* pring[3];
  int pquar[3];
  {
    int pi = 0;
    for (int qq = 0; qq < 4; ++qq)
      if (qq != q) { pring[pi] = ring + (size_t)(16 + g * 4 + qq) * 4096; pquar[pi] = qq; ++pi; }
  }
  u64* myring = ring + (size_t)(16 + g * 4 + q) * 4096;

  for (int u = 0; u < T_SEQ; ++u) {
    f32x4 acc = {bv, bv, bv, bv};
    const unsigned htag = (unsigned)(u + 1);

    const u64* hb = hist + ((size_t)(u * 16 + g * 4) * 512 + tid) * 2;
    const u64* h0a = hb, *h1a = hb + 1024, *h2a = hb + 2048, *h3a = hb + 3072;
    const int slot = (u - 1) & 3;
    const u64* a0 = pring[0] + (size_t)slot * 1024 + tid * 2;
    const u64* a1 = pring[1] + (size_t)slot * 1024 + tid * 2;
    const u64* a2 = pring[2] + (size_t)slot * 1024 + tid * 2;
    u32x4 hv0, hv1, hv2, hv3, r0, r1, r2;

    issue4x16(h0a, h1a, h2a, h3a, hv0, hv1, hv2, hv3);  // hist first
    if (u > 0) {
      issue3x16(a0, a1, a2, r0, r1, r2);                // then ring
#pragma unroll
      for (int i = 0; i < 4; ++i) {                     // own-quarter Whh (alds u-1)
        const int kc = q * 4 + i;
        f16x8 a = *(const f16x8*)&alds[kc * 512 + lane * 8];
        acc = __builtin_amdgcn_mfma_f32_16x16x32_f16(
            a, __builtin_bit_cast(f16x8, Bh[i]), acc, 0, 0, 0);
      }
      wait4_v3(hv0, hv1, hv2, hv3);                     // hist done, ring in flight
    } else {
      wait4_v0(hv0, hv1, hv2, hv3);
    }
    if (__any((hv0.z != htag) | (hv1.z != htag) | (hv2.z != htag) | (hv3.z != htag))) {
      // slow path (early steps, before layer-0 gets ahead)
      do {
        load4x16_sys(h0a, h1a, h2a, h3a, hv0, hv1, hv2, hv3);  // drains ring too
      } while (__any((hv0.z != htag) | (hv1.z != htag) |
                     (hv2.z != htag) | (hv3.z != htag)));
      if (u > 0) issue3x16(a0, a1, a2, r0, r1, r2);            // re-issue ring
    }
    xldsu[0 * 512 + tid] = ((u64)hv0.y << 32) | hv0.x;
    xldsu[1 * 512 + tid] = ((u64)hv1.y << 32) | hv1.x;
    xldsu[2 * 512 + tid] = ((u64)hv2.y << 32) | hv2.x;
    xldsu[3 * 512 + tid] = ((u64)hv3.y << 32) | hv3.x;
    __syncthreads();  // bar_X: h0 plane ready

#pragma unroll
    for (int kc = 0; kc < 16; ++kc) {   // xw1 MFMAs cover the ring detect
      f16x8 a = *(const f16x8*)&xlds[kc * 512 + lane * 8];
      acc = __builtin_amdgcn_mfma_f32_16x16x32_f16(
          a, __builtin_bit_cast(f16x8, Bx[kc]), acc, 0, 0, 0);
    }

    if (u > 0) {
      const unsigned wtag = (unsigned)u;
      wait3(r0, r1, r2);
      while ((r0.z != wtag) | (r1.z != wtag) | (r2.z != wtag))
        load3x16_sys(a0, a1, a2, r0, r1, r2);
      aldsu[pquar[0] * 512 + tid] = ((u64)r0.y << 32) | r0.x;
      aldsu[pquar[1] * 512 + tid] = ((u64)r1.y << 32) | r1.x;
      aldsu[pquar[2] * 512 + tid] = ((u64)r2.y << 32) | r2.x;
      __syncthreads();  // bar_A: h1[u-1] plane complete

      if (q == 0) {     // dump h1[u-1] plane for logits/hlast
        u64* dst = (u64*)h1A + ((size_t)(u - 1) * 4 + g) * 2048;
#pragma unroll
        for (int i = 0; i < 4; ++i)
          dst[tid + 512 * i] = aldsu[tid + 512 * i];
      }
#pragma unroll
      for (int i = 4; i < 16; ++i) {
        const int kc = (q * 4 + i) & 15;
        f16x8 a = *(const f16x8*)&alds[kc * 512 + lane * 8];
        acc = __builtin_amdgcn_mfma_f32_16x16x32_f16(
            a, __builtin_bit_cast(f16x8, Bh[i]), acc, 0, 0, 0);
      }
    }
    __syncthreads();    // bar1: all alds/xlds reads done before overwrite
    {
      const int n = n0 + l15;
      const int kc = n >> 5, qd = (n >> 3) & 3, j = n & 7;
#pragma unroll
      for (int r = 0; r < 4; ++r)
        alds[kc * 512 + (qd * 16 + quad * 4 + r) * 8 + j] = (_Float16)fast_tanh(acc[r]);
    }
    __syncthreads();    // bar2
    {
      u64 v = aldsu[q * 512 + tid];
      store16_sys(myring + (size_t)(u & 3) * 1024 + tid * 2, v, (unsigned)(u + 1));
    }
  }

  // epilogue: q0 assembles and dumps h1[511]
  if (q == 0) {
    const int slot = (T_SEQ - 1) & 3;
    const u64* a0 = pring[0] + (size_t)slot * 1024 + tid * 2;
    const u64* a1 = pring[1] + (size_t)slot * 1024 + tid * 2;
    const u64* a2 = pring[2] + (size_t)slot * 1024 + tid * 2;
    u32x4 r0, r1, r2;
    load3x16_sys(a0, a1, a2, r0, r1, r2);
    const unsigned wtag = (unsigned)T_SEQ;
    while ((r0.z != wtag) | (r1.z != wtag) | (r2.z != wtag))
      load3x16_sys(a0, a1, a2, r0, r1, r2);
    aldsu[pquar[0] * 512 + tid] = ((u64)r0.y << 32) | r0.x;
    aldsu[pquar[1] * 512 + tid] = ((u64)r1.y << 32) | r1.x;
    aldsu[pquar[2] * 512 + tid] = ((u64)r2.y << 32) | r2.x;
    __syncthreads();
    u64* dst = (u64*)h1A + ((size_t)(T_SEQ - 1) * 4 + g) * 2048;
#pragma unroll
    for (int i = 0; i < 4; ++i)
      dst[tid + 512 * i] = aldsu[tid + 512 * i];
  }
}

// Fused two-layer recurrence: 32 co-resident blocks (<< 256 CUs).
// bid<16: layer 0 (groups x quarters as before). bid>=16: layer 1, lag-1
// pipelined on layer 0's tagged history; xw1 fused (replaces xw1_kernel).
__global__ __launch_bounds__(512, 2) void rnn_fused_kernel(
    const _Float16* __restrict__ Whh0, const _Float16* __restrict__ xwf0,
    const _Float16* __restrict__ Whh1, const _Float16* __restrict__ Wxh1,
    const float* __restrict__ bh1,
    u64* __restrict__ ring, u64* __restrict__ hist, _Float16* __restrict__ h1A) {
  __shared__ _Float16 lds[32 * 512];   // layer0: first 16KB; layer1: both halves
  const int bid = blockIdx.x, tid = threadIdx.x;
  if (bid < 16) {
    layer0_loop(Whh0, xwf0, ring, hist, lds, bid & 3, bid >> 2, tid);
  } else {
    const int b = bid - 16;
    layer1_loop(Whh1, Wxh1, bh1, hist, ring, h1A, lds, lds + 16 * 512,
                b & 3, b >> 2, tid);
  }
}

// logits[b][t][v] = h1[t,b][:] . Why[v][:] + by[v]; h1 in A-frag layout. Grid 512 x 256.
__global__ __launch_bounds__(256) void logits_kernel(
    const _Float16* __restrict__ h1A, const _Float16* __restrict__ Why,
    const float* __restrict__ by, float* __restrict__ out) {
  const int t = blockIdx.x;
  const int wv = threadIdx.x >> 6, lane = threadIdx.x & 63;
  const int l15 = lane & 15, quad = lane >> 4, bb = wv * 16;
  f32x4 acc[8];
#pragma unroll
  for (int vt = 0; vt < 8; ++vt) { float bvv = by[vt * 16 + l15]; acc[vt] = {bvv, bvv, bvv, bvv}; }
#pragma unroll
  for (int kc = 0; kc < 16; ++kc) {
    f16x8 a = *(const f16x8*)&h1A[(((size_t)t * 4 + wv) * 16 + kc) * 512 + lane * 8];
#pragma unroll
    for (int vt = 0; vt < 8; ++vt) {
      f16x8 b = *(const f16x8*)&Why[(size_t)(vt * 16 + l15) * 512 + kc * 32 + quad * 8];
      acc[vt] = __builtin_amdgcn_mfma_f32_16x16x32_f16(a, b, acc[vt], 0, 0, 0);
    }
  }
#pragma unroll
  for (int vt = 0; vt < 8; ++vt)
#pragma unroll
    for (int r = 0; r < 4; ++r)
      out[((size_t)(bb + quad * 4 + r) * 512 + t) * 128 + vt * 16 + l15] = acc[vt][r];
}

// h_last: h0 from tagged history (t=511), h1 from h1A plane.
__global__ void hlast_kernel(const u64* __restrict__ hist,
                             const _Float16* __restrict__ h1A,
                             float* __restrict__ out) {
  const size_t LOG = (size_t)BATCH * T_SEQ * VOC;
  const size_t HL = (size_t)BATCH * HID;
  int tid = blockIdx.x * 256 + threadIdx.x;
  if (tid < (int)HL) {
    const int b = tid >> 9, n = tid & 511;
    const int gg = b >> 4, m = b & 15;
    const int kc = n >> 5, qd = (n >> 3) & 3, j = n & 7;
    const int pf = kc * 512 + (qd * 16 + m) * 8 + j;   // plane-local f16 index
    const int p = pf >> 2;                              // plane u64 index
    const u64 d = hist[(((size_t)(T_SEQ - 1) * 16 + gg * 4 + (p >> 9)) * 512 + (p & 511)) * 2];
    out[LOG + tid] = (float)u2h((unsigned short)(d >> ((pf & 3) * 16)));
    const size_t idx = (((size_t)(T_SEQ - 1) * 4 + gg) * 16 + kc) * 512 + (qd * 16 + m) * 8 + j;
    out[LOG + HL + tid] = (float)h1A[idx];
  }
}

extern "C" void kernel_launch(void* const* d_in, const int* in_sizes, int n_in,
                              void* d_out, int out_size, void* d_ws, size_t ws_size,
                              hipStream_t stream) {
  const int* x = (const int*)d_in[0];
  float* out = (float*)d_out;
  char* ws = (char*)d_ws;
  u64* ring = (u64*)(ws + OFF_RING);
  u64* hist = (u64*)(ws + OFF_HIST);
  _Float16* arena = (_Float16*)(ws + OFF_ARENA);
  _Float16* xw0f = (_Float16*)(ws + OFF_XW0);
  _Float16* h1A  = (_Float16*)(ws + OFF_H1A);

  canon_kernel<<<512, 256, 0, stream>>>(
      (const float*)d_in[1], (const float*)d_in[2], (const float*)d_in[3],
      (const float*)d_in[5], (const float*)d_in[6], (const float*)d_in[8],
      arena, (int*)ring);

  xw0_kernel<<<dim3(512, 8), 256, 0, stream>>>(
      x, arena + AOFF_EMB, arena + AOFF_WXH0, (const float*)d_in[4], xw0f);

  rnn_fused_kernel<<<32, 512, 0, stream>>>(
      arena + AOFF_WHH0, xw0f,
      arena + AOFF_WHH1, arena + AOFF_WXH1, (const float*)d_in[7],
      ring, hist, h1A);

  logits_kernel<<<512, 256, 0, stream>>>(
      h1A, arena + AOFF_WHY, (const float*)d_in[9], out);

  hlast_kernel<<<(BATCH * HID + 255) / 256, 256, 0, stream>>>(hist, h1A, out);
}

// Round 8
// 1197.939 us; speedup vs baseline: 3.4785x; 1.0674x over previous
//
#include <hip/hip_runtime.h>
#include <hip/hip_fp16.h>

typedef _Float16 f16x8 __attribute__((ext_vector_type(8)));
typedef float f32x4 __attribute__((ext_vector_type(4)));
typedef unsigned int u32x4 __attribute__((ext_vector_type(4)));
typedef unsigned int u32x2 __attribute__((ext_vector_type(2)));
typedef unsigned long long u64;

static constexpr int T_SEQ = 512;
static constexpr int BATCH = 64;
static constexpr int HID   = 512;
static constexpr int VOC   = 128;

// ---- fp16 arena element offsets ----
static constexpr int AOFF_EMB  = 0;        // 128*256
static constexpr int AOFF_WXH0 = 32768;    // 512*256
static constexpr int AOFF_WHH0 = 163840;   // 512*512
static constexpr int AOFF_WXH1 = 425984;   // 512*512
static constexpr int AOFF_WHH1 = 688128;   // 512*512
static constexpr int AOFF_WHY  = 950272;   // 128*512
static constexpr int ATOT      = 1015808;

// ---- ws byte offsets (identical budget to R6-proven 137.3 MB) ----
// ring: tagged 16B entries, 32 regions (only 16..31 used, by layer 1).
static constexpr size_t OFF_RING   = 16384;
static constexpr size_t RING_BYTES = 32ull * 4 * 512 * 16;            // 1 MB
// hist: full-length tagged h0 history [t][g][q][tid] 16B = 64 MB.
static constexpr size_t OFF_HIST   = OFF_RING + RING_BYTES;           // 1,064,960
static constexpr size_t HIST_BYTES = 512ull * 16 * 512 * 16;          // 67,108,864
static constexpr size_t OFF_ARENA  = OFF_HIST + HIST_BYTES;           // 68,173,824
static constexpr size_t OFF_XW0    = OFF_ARENA + 2ull * ATOT;         // 70,205,440
static constexpr size_t PLANE_B    = (size_t)T_SEQ * BATCH * HID * 2; // 32 MB
static constexpr size_t OFF_H1A    = OFF_XW0 + PLANE_B;               // 103,759,872

__device__ __forceinline__ unsigned short h2u(_Float16 h) {
  union { _Float16 h; unsigned short u; } c; c.h = h; return c.u;
}
__device__ __forceinline__ _Float16 u2h(unsigned short u) {
  union { unsigned short u; _Float16 h; } c; c.u = u; return c.h;
}
__device__ __forceinline__ float fast_tanh(float x) {
  float e = __expf(2.0f * x);
  return 1.0f - 2.0f * __builtin_amdgcn_rcpf(e + 1.0f);
}

// ---- tagged 16B message primitives (single-transaction data+tag) ----
__device__ __forceinline__ void store16_sys(u64* addr, u64 data, unsigned tag) {
  u32x4 v;
  v.x = (unsigned)data; v.y = (unsigned)(data >> 32);
  v.z = tag;            v.w = 0u;
  asm volatile("global_store_dwordx4 %0, %1, off sc0 sc1"
               :: "v"(addr), "v"(v) : "memory");
}
__device__ __forceinline__ void issue3x16(const u64* a, const u64* b, const u64* c,
                                          u32x4& v0, u32x4& v1, u32x4& v2) {
  asm volatile("global_load_dwordx4 %0, %3, off sc0 sc1\n\t"
               "global_load_dwordx4 %1, %4, off sc0 sc1\n\t"
               "global_load_dwordx4 %2, %5, off sc0 sc1"
               : "=&v"(v0), "=&v"(v1), "=&v"(v2)
               : "v"(a), "v"(b), "v"(c)
               : "memory");
}
__device__ __forceinline__ void issue4x16(const u64* a, const u64* b, const u64* c,
                                          const u64* d, u32x4& v0, u32x4& v1,
                                          u32x4& v2, u32x4& v3) {
  asm volatile("global_load_dwordx4 %0, %4, off sc0 sc1\n\t"
               "global_load_dwordx4 %1, %5, off sc0 sc1\n\t"
               "global_load_dwordx4 %2, %6, off sc0 sc1\n\t"
               "global_load_dwordx4 %3, %7, off sc0 sc1"
               : "=&v"(v0), "=&v"(v1), "=&v"(v2), "=&v"(v3)
               : "v"(a), "v"(b), "v"(c), "v"(d)
               : "memory");
}
__device__ __forceinline__ void wait3(u32x4& v0, u32x4& v1, u32x4& v2) {
  asm volatile("s_waitcnt vmcnt(0)" : "+v"(v0), "+v"(v1), "+v"(v2) :: "memory");
}
__device__ __forceinline__ void wait4_v3(u32x4& v0, u32x4& v1, u32x4& v2, u32x4& v3) {
  asm volatile("s_waitcnt vmcnt(3)" : "+v"(v0), "+v"(v1), "+v"(v2), "+v"(v3) :: "memory");
}
__device__ __forceinline__ void wait4_v0(u32x4& v0, u32x4& v1, u32x4& v2, u32x4& v3) {
  asm volatile("s_waitcnt vmcnt(0)" : "+v"(v0), "+v"(v1), "+v"(v2), "+v"(v3) :: "memory");
}
__device__ __forceinline__ void load3x16_sys(const u64* a, const u64* b, const u64* c,
                                             u32x4& v0, u32x4& v1, u32x4& v2) {
  asm volatile("global_load_dwordx4 %0, %3, off sc0 sc1\n\t"
               "global_load_dwordx4 %1, %4, off sc0 sc1\n\t"
               "global_load_dwordx4 %2, %5, off sc0 sc1\n\t"
               "s_waitcnt vmcnt(0)"
               : "=&v"(v0), "=&v"(v1), "=&v"(v2)
               : "v"(a), "v"(b), "v"(c)
               : "memory");
}
__device__ __forceinline__ void load4x16_sys(const u64* a, const u64* b, const u64* c,
                                             const u64* d, u32x4& v0, u32x4& v1,
                                             u32x4& v2, u32x4& v3) {
  asm volatile("global_load_dwordx4 %0, %4, off sc0 sc1\n\t"
               "global_load_dwordx4 %1, %5, off sc0 sc1\n\t"
               "global_load_dwordx4 %2, %6, off sc0 sc1\n\t"
               "global_load_dwordx4 %3, %7, off sc0 sc1\n\t"
               "s_waitcnt vmcnt(0)"
               : "=&v"(v0), "=&v"(v1), "=&v"(v2), "=&v"(v3)
               : "v"(a), "v"(b), "v"(c), "v"(d)
               : "memory");
}

// fp32 params -> fp16 arena; zero ring+hist (contiguous).
__global__ __launch_bounds__(256) void canon_kernel(
    const float* p0, const float* p1, const float* p2, const float* p3,
    const float* p4, const float* p5, _Float16* __restrict__ dst,
    int* __restrict__ ringhist) {
  const int NZ = (int)((RING_BYTES + HIST_BYTES) / 4);
  for (int i = blockIdx.x * 256 + threadIdx.x; i < NZ; i += gridDim.x * 256)
    ringhist[i] = 0;
  const float* srcs[6] = {p0, p1, p2, p3, p4, p5};
  const int ns[6] = {32768, 131072, 262144, 262144, 262144, 65536};
  for (int i = blockIdx.x * 256 + threadIdx.x; i < ATOT; i += gridDim.x * 256) {
    int off = i, s = 0;
    while (off >= ns[s]) { off -= ns[s]; ++s; }
    dst[i] = (_Float16)srcs[s][off];
  }
}

// xwf0[t][n][b] = emb[x[b,t]][:] . Wxh0[n][:] + bh0[n].  Grid (512, 8) x 256.
__global__ __launch_bounds__(256) void xw0_kernel(
    const int* __restrict__ x, const _Float16* __restrict__ emb,
    const _Float16* __restrict__ Wxh, const float* __restrict__ bh,
    _Float16* __restrict__ xwf) {
  __shared__ _Float16 Bs[64][264];
  const int t = blockIdx.x, n0 = blockIdx.y * 64, tid = threadIdx.x;
#pragma unroll
  for (int rep = 0; rep < 8; ++rep) {
    int flat = rep * 256 + tid;
    int row = flat >> 5, c8 = flat & 31;
    *(f16x8*)&Bs[row][c8 * 8] = *(const f16x8*)&Wxh[(size_t)(n0 + row) * 256 + c8 * 8];
  }
  __syncthreads();
  const int wv = tid >> 6, lane = tid & 63, l15 = lane & 15, quad = lane >> 4;
  const int b = wv * 16 + l15;
  const int idx = x[b * 512 + t];
  f32x4 acc[4];
#pragma unroll
  for (int nt = 0; nt < 4; ++nt) { float bv = bh[n0 + nt * 16 + l15]; acc[nt] = {bv, bv, bv, bv}; }
#pragma unroll
  for (int kc = 0; kc < 8; ++kc) {
    f16x8 a = *(const f16x8*)&emb[(size_t)idx * 256 + kc * 32 + quad * 8];
#pragma unroll
    for (int nt = 0; nt < 4; ++nt) {
      f16x8 bf = *(const f16x8*)&Bs[nt * 16 + l15][kc * 32 + quad * 8];
      acc[nt] = __builtin_amdgcn_mfma_f32_16x16x32_f16(a, bf, acc[nt], 0, 0, 0);
    }
  }
#pragma unroll
  for (int nt = 0; nt < 4; ++nt) {
    unsigned int lo = (unsigned int)h2u((_Float16)acc[nt][0]) |
                      ((unsigned int)h2u((_Float16)acc[nt][1]) << 16);
    unsigned int hi = (unsigned int)h2u((_Float16)acc[nt][2]) |
                      ((unsigned int)h2u((_Float16)acc[nt][3]) << 16);
    u32x2 pk = {lo, hi};
    *(u32x2*)&xwf[(size_t)t * 32768 + (size_t)(n0 + nt * 16 + l15) * 64 + wv * 16 + quad * 4] = pk;
  }
}

// ---- layer-0: partners poll hist directly (full-length, never-reused slots).
// Early publish: tanh -> intra-wave LDS transpose (message u64 q*512+tid for
// tid in wave wv is assembled ONLY from wave wv's lanes; index algebra
// verified) -> lgkmcnt fence -> store16 -> bar2.
__device__ __forceinline__ void layer0_loop(
    const _Float16* __restrict__ Whh, const _Float16* __restrict__ xwf,
    u64* __restrict__ hist, _Float16* alds, const int g, const int q, const int tid) {
  u64* aldsu = (u64*)alds;
  const int lane = tid & 63, wv = tid >> 6, l15 = lane & 15, quad = lane >> 4;
  const int n0 = q * 128 + wv * 16;

  u32x4 Bw[16];
#pragma unroll
  for (int i = 0; i < 16; ++i) {
    const int kc = (q * 4 + i) & 15;
    Bw[i] = *(const u32x4*)&Whh[(size_t)(n0 + l15) * 512 + kc * 32 + quad * 8];
  }

  int pquar[3];
  {
    int pi = 0;
    for (int qq = 0; qq < 4; ++qq)
      if (qq != q) pquar[pi++] = qq;
  }

  const _Float16* xwb = xwf + (size_t)(n0 + l15) * 64 + g * 16 + quad * 4;
  u32x2 pfx = *(const u32x2*)xwb;

  for (int t = 0; t < T_SEQ; ++t) {
    // pin weights in VGPRs each iteration (needs the 256-VGPR cap: lb(512,1))
#pragma unroll
    for (int i = 0; i < 16; ++i) asm volatile("" : "+v"(Bw[i]));

    f32x4 accA, accB = {0.f, 0.f, 0.f, 0.f};
    accA[0] = (float)u2h((unsigned short)(pfx.x & 0xFFFFu));
    accA[1] = (float)u2h((unsigned short)(pfx.x >> 16));
    accA[2] = (float)u2h((unsigned short)(pfx.y & 0xFFFFu));
    accA[3] = (float)u2h((unsigned short)(pfx.y >> 16));
    if (t + 1 < T_SEQ) pfx = *(const u32x2*)(xwb + (size_t)(t + 1) * 32768);

    if (t > 0) {
      const u64* a0 = hist + (((size_t)(t - 1) * 16 + g * 4 + pquar[0]) * 512 + tid) * 2;
      const u64* a1 = hist + (((size_t)(t - 1) * 16 + g * 4 + pquar[1]) * 512 + tid) * 2;
      const u64* a2 = hist + (((size_t)(t - 1) * 16 + g * 4 + pquar[2]) * 512 + tid) * 2;
      u32x4 r0, r1, r2;
      issue3x16(a0, a1, a2, r0, r1, r2);   // poll #1 under own MFMAs

#pragma unroll
      for (int i = 0; i < 4; ++i) {        // own-quarter chain -> accA
        const int kc = q * 4 + i;
        f16x8 a = *(const f16x8*)&alds[kc * 512 + lane * 8];
        accA = __builtin_amdgcn_mfma_f32_16x16x32_f16(
            a, __builtin_bit_cast(f16x8, Bw[i]), accA, 0, 0, 0);
      }

      wait3(r0, r1, r2);
      const unsigned wtag = (unsigned)t;
      while ((r0.z != wtag) | (r1.z != wtag) | (r2.z != wtag))
        load3x16_sys(a0, a1, a2, r0, r1, r2);

      aldsu[pquar[0] * 512 + tid] = ((u64)r0.y << 32) | r0.x;
      aldsu[pquar[1] * 512 + tid] = ((u64)r1.y << 32) | r1.x;
      aldsu[pquar[2] * 512 + tid] = ((u64)r2.y << 32) | r2.x;
      __syncthreads();  // bar_A

#pragma unroll
      for (int i = 4; i < 16; ++i) {       // partner kcs, 2 chains
        const int kc = (q * 4 + i) & 15;
        f16x8 a = *(const f16x8*)&alds[kc * 512 + lane * 8];
        if (i & 1)
          accB = __builtin_amdgcn_mfma_f32_16x16x32_f16(
              a, __builtin_bit_cast(f16x8, Bw[i]), accB, 0, 0, 0);
        else
          accA = __builtin_amdgcn_mfma_f32_16x16x32_f16(
              a, __builtin_bit_cast(f16x8, Bw[i]), accA, 0, 0, 0);
      }
      __syncthreads();  // bar1
    }

    // tanh + stage own cols (A-frag order)
    {
      f32x4 s = accA + accB;
      const int n = n0 + l15;
      const int kc = n >> 5, qd = (n >> 3) & 3, j = n & 7;
#pragma unroll
      for (int r = 0; r < 4; ++r)
        alds[kc * 512 + (qd * 16 + quad * 4 + r) * 8 + j] = (_Float16)fast_tanh(s[r]);
    }
    // intra-wave transpose complete -> publish BEFORE the block barrier
    asm volatile("s_waitcnt lgkmcnt(0)" ::: "memory");
    __builtin_amdgcn_sched_barrier(0);
    {
      u64 msg = aldsu[q * 512 + tid];
      store16_sys(hist + (((size_t)t * 16 + g * 4 + q) * 512 + tid) * 2,
                  msg, (unsigned)(t + 1));
    }
    __syncthreads();    // bar2: block-wide A-plane visibility for next step
  }
}

// ---- layer-1: fused xw1 + recurrence, lag-1 on hist; ring for own exchange.
__device__ __forceinline__ void layer1_loop(
    const _Float16* __restrict__ Whh, const _Float16* __restrict__ Wxh,
    const float* __restrict__ bh, const u64* __restrict__ hist,
    u64* __restrict__ ring, _Float16* __restrict__ h1A,
    _Float16* alds, _Float16* xlds, const int g, const int q, const int tid) {
  u64* aldsu = (u64*)alds;
  u64* xldsu = (u64*)xlds;
  const int lane = tid & 63, wv = tid >> 6, l15 = lane & 15, quad = lane >> 4;
  const int n0 = q * 128 + wv * 16;

  u32x4 Bh[16], Bx[16];
#pragma unroll
  for (int i = 0; i < 16; ++i) {
    const int kc = (q * 4 + i) & 15;
    Bh[i] = *(const u32x4*)&Whh[(size_t)(n0 + l15) * 512 + kc * 32 + quad * 8];
  }
#pragma unroll
  for (int i = 0; i < 16; ++i)
    Bx[i] = *(const u32x4*)&Wxh[(size_t)(n0 + l15) * 512 + i * 32 + quad * 8];
  const float bv = bh[n0 + l15];

  u64* pring[3];
  int pquar[3];
  {
    int pi = 0;
    for (int qq = 0; qq < 4; ++qq)
      if (qq != q) { pring[pi] = ring + (size_t)(16 + g * 4 + qq) * 4096; pquar[pi] = qq; ++pi; }
  }
  u64* myring = ring + (size_t)(16 + g * 4 + q) * 4096;

  for (int u = 0; u < T_SEQ; ++u) {
#pragma unroll
    for (int i = 0; i < 16; ++i) asm volatile("" : "+v"(Bh[i]));
#pragma unroll
    for (int i = 0; i < 16; ++i) asm volatile("" : "+v"(Bx[i]));

    f32x4 accA = {bv, bv, bv, bv};
    f32x4 accB = {0.f, 0.f, 0.f, 0.f}, accC = {0.f, 0.f, 0.f, 0.f},
          accD = {0.f, 0.f, 0.f, 0.f};
    const unsigned htag = (unsigned)(u + 1);

    const u64* hb = hist + ((size_t)(u * 16 + g * 4) * 512 + tid) * 2;
    const u64* h0a = hb, *h1a = hb + 1024, *h2a = hb + 2048, *h3a = hb + 3072;
    const int slot = (u - 1) & 3;
    const u64* a0 = pring[0] + (size_t)slot * 1024 + tid * 2;
    const u64* a1 = pring[1] + (size_t)slot * 1024 + tid * 2;
    const u64* a2 = pring[2] + (size_t)slot * 1024 + tid * 2;
    u32x4 hv0, hv1, hv2, hv3, r0, r1, r2;

    issue4x16(h0a, h1a, h2a, h3a, hv0, hv1, hv2, hv3);  // hist first
    if (u > 0) {
      issue3x16(a0, a1, a2, r0, r1, r2);                // then ring
#pragma unroll
      for (int i = 0; i < 4; ++i) {                     // own-quarter Whh -> accA
        const int kc = q * 4 + i;
        f16x8 a = *(const f16x8*)&alds[kc * 512 + lane * 8];
        accA = __builtin_amdgcn_mfma_f32_16x16x32_f16(
            a, __builtin_bit_cast(f16x8, Bh[i]), accA, 0, 0, 0);
      }
      wait4_v3(hv0, hv1, hv2, hv3);                     // hist done, ring in flight
    } else {
      wait4_v0(hv0, hv1, hv2, hv3);
    }
    if (__any((hv0.z != htag) | (hv1.z != htag) | (hv2.z != htag) | (hv3.z != htag))) {
      do {
        load4x16_sys(h0a, h1a, h2a, h3a, hv0, hv1, hv2, hv3);  // drains ring too
      } while (__any((hv0.z != htag) | (hv1.z != htag) |
                     (hv2.z != htag) | (hv3.z != htag)));
      if (u > 0) issue3x16(a0, a1, a2, r0, r1, r2);            // re-issue ring
    }
    xldsu[0 * 512 + tid] = ((u64)hv0.y << 32) | hv0.x;
    xldsu[1 * 512 + tid] = ((u64)hv1.y << 32) | hv1.x;
    xldsu[2 * 512 + tid] = ((u64)hv2.y << 32) | hv2.x;
    xldsu[3 * 512 + tid] = ((u64)hv3.y << 32) | hv3.x;
    __syncthreads();  // bar_X: h0 plane ready

#pragma unroll
    for (int kc = 0; kc < 16; ++kc) {   // xw1, 2 chains (B: kc<8, C: kc>=8)
      f16x8 a = *(const f16x8*)&xlds[kc * 512 + lane * 8];
      if (kc < 8)
        accB = __builtin_amdgcn_mfma_f32_16x16x32_f16(
            a, __builtin_bit_cast(f16x8, Bx[kc]), accB, 0, 0, 0);
      else
        accC = __builtin_amdgcn_mfma_f32_16x16x32_f16(
            a, __builtin_bit_cast(f16x8, Bx[kc]), accC, 0, 0, 0);
    }

    if (u > 0) {
      const unsigned wtag = (unsigned)u;
      wait3(r0, r1, r2);
      while ((r0.z != wtag) | (r1.z != wtag) | (r2.z != wtag))
        load3x16_sys(a0, a1, a2, r0, r1, r2);

      if (q == 0) {   // dump partner quarters of h1[u-1] straight from regs
        u64* dplane = (u64*)h1A + ((size_t)(u - 1) * 4 + g) * 2048;
        dplane[pquar[0] * 512 + tid] = ((u64)r0.y << 32) | r0.x;
        dplane[pquar[1] * 512 + tid] = ((u64)r1.y << 32) | r1.x;
        dplane[pquar[2] * 512 + tid] = ((u64)r2.y << 32) | r2.x;
      }
      aldsu[pquar[0] * 512 + tid] = ((u64)r0.y << 32) | r0.x;
      aldsu[pquar[1] * 512 + tid] = ((u64)r1.y << 32) | r1.x;
      aldsu[pquar[2] * 512 + tid] = ((u64)r2.y << 32) | r2.x;
      __syncthreads();  // bar_A

#pragma unroll
      for (int i = 4; i < 16; ++i) {    // partner Whh, 2 chains (A/D)
        const int kc = (q * 4 + i) & 15;
        f16x8 a = *(const f16x8*)&alds[kc * 512 + lane * 8];
        if (i & 1)
          accD = __builtin_amdgcn_mfma_f32_16x16x32_f16(
              a, __builtin_bit_cast(f16x8, Bh[i]), accD, 0, 0, 0);
        else
          accA = __builtin_amdgcn_mfma_f32_16x16x32_f16(
              a, __builtin_bit_cast(f16x8, Bh[i]), accA, 0, 0, 0);
      }
    }
    __syncthreads();    // bar1: all alds/xlds reads done before overwrite
    {
      f32x4 s = (accA + accD) + (accB + accC);
      const int n = n0 + l15;
      const int kc = n >> 5, qd = (n >> 3) & 3, j = n & 7;
#pragma unroll
      for (int r = 0; r < 4; ++r)
        alds[kc * 512 + (qd * 16 + quad * 4 + r) * 8 + j] = (_Float16)fast_tanh(s[r]);
    }
    asm volatile("s_waitcnt lgkmcnt(0)" ::: "memory");
    __builtin_amdgcn_sched_barrier(0);
    {
      u64 msg = aldsu[q * 512 + tid];
      store16_sys(myring + (size_t)(u & 3) * 1024 + tid * 2, msg, (unsigned)(u + 1));
      if (q == 0)     // own quarter of h1[u] straight from the message
        ((u64*)h1A)[((size_t)u * 4 + g) * 2048 + tid] = msg;
    }
    __syncthreads();    // bar2
  }

  // epilogue: q0 collects partners' h1[511] (own quarter already dumped)
  if (q == 0) {
    const int slot = (T_SEQ - 1) & 3;
    const u64* a0 = pring[0] + (size_t)slot * 1024 + tid * 2;
    const u64* a1 = pring[1] + (size_t)slot * 1024 + tid * 2;
    const u64* a2 = pring[2] + (size_t)slot * 1024 + tid * 2;
    u32x4 r0, r1, r2;
    load3x16_sys(a0, a1, a2, r0, r1, r2);
    const unsigned wtag = (unsigned)T_SEQ;
    while ((r0.z != wtag) | (r1.z != wtag) | (r2.z != wtag))
      load3x16_sys(a0, a1, a2, r0, r1, r2);
    u64* dplane = (u64*)h1A + ((size_t)(T_SEQ - 1) * 4 + g) * 2048;
    dplane[pquar[0] * 512 + tid] = ((u64)r0.y << 32) | r0.x;
    dplane[pquar[1] * 512 + tid] = ((u64)r1.y << 32) | r1.x;
    dplane[pquar[2] * 512 + tid] = ((u64)r2.y << 32) | r2.x;
  }
}

// Fused two-layer recurrence: 32 blocks on 256 CUs -> each block gets its own
// CU. __launch_bounds__(512, 1) = 256-VGPR cap so layer-1's 128 pinned weight
// VGPRs + working set (~210) fit. (512,2)'s 128-VGPR cap made R7's pins
// infeasible -> RA/compile failure.
__global__ __launch_bounds__(512, 1) void rnn_fused_kernel(
    const _Float16* __restrict__ Whh0, const _Float16* __restrict__ xwf0,
    const _Float16* __restrict__ Whh1, const _Float16* __restrict__ Wxh1,
    const float* __restrict__ bh1,
    u64* __restrict__ ring, u64* __restrict__ hist, _Float16* __restrict__ h1A) {
  __shared__ _Float16 lds[32 * 512];   // layer0: first 16KB; layer1: both halves
  const int bid = blockIdx.x, tid = threadIdx.x;
  if (bid < 16) {
    layer0_loop(Whh0, xwf0, hist, lds, bid & 3, bid >> 2, tid);
  } else {
    const int b = bid - 16;
    layer1_loop(Whh1, Wxh1, bh1, hist, ring, h1A, lds, lds + 16 * 512,
                b & 3, b >> 2, tid);
  }
}

// logits[b][t][v] = h1[t,b][:] . Why[v][:] + by[v]; h1 in A-frag layout. Grid 512 x 256.
__global__ __launch_bounds__(256) void logits_kernel(
    const _Float16* __restrict__ h1A, const _Float16* __restrict__ Why,
    const float* __restrict__ by, float* __restrict__ out) {
  const int t = blockIdx.x;
  const int wv = threadIdx.x >> 6, lane = threadIdx.x & 63;
  const int l15 = lane & 15, quad = lane >> 4, bb = wv * 16;
  f32x4 acc[8];
#pragma unroll
  for (int vt = 0; vt < 8; ++vt) { float bvv = by[vt * 16 + l15]; acc[vt] = {bvv, bvv, bvv, bvv}; }
#pragma unroll
  for (int kc = 0; kc < 16; ++kc) {
    f16x8 a = *(const f16x8*)&h1A[(((size_t)t * 4 + wv) * 16 + kc) * 512 + lane * 8];
#pragma unroll
    for (int vt = 0; vt < 8; ++vt) {
      f16x8 b = *(const f16x8*)&Why[(size_t)(vt * 16 + l15) * 512 + kc * 32 + quad * 8];
      acc[vt] = __builtin_amdgcn_mfma_f32_16x16x32_f16(a, b, acc[vt], 0, 0, 0);
    }
  }
#pragma unroll
  for (int vt = 0; vt < 8; ++vt)
#pragma unroll
    for (int r = 0; r < 4; ++r)
      out[((size_t)(bb + quad * 4 + r) * 512 + t) * 128 + vt * 16 + l15] = acc[vt][r];
}

// h_last: h0 from tagged history (t=511), h1 from h1A plane.
__global__ void hlast_kernel(const u64* __restrict__ hist,
                             const _Float16* __restrict__ h1A,
                             float* __restrict__ out) {
  const size_t LOG = (size_t)BATCH * T_SEQ * VOC;
  const size_t HL = (size_t)BATCH * HID;
  int tid = blockIdx.x * 256 + threadIdx.x;
  if (tid < (int)HL) {
    const int b = tid >> 9, n = tid & 511;
    const int gg = b >> 4, m = b & 15;
    const int kc = n >> 5, qd = (n >> 3) & 3, j = n & 7;
    const int pf = kc * 512 + (qd * 16 + m) * 8 + j;   // plane-local f16 index
    const int p = pf >> 2;                              // plane u64 index
    const u64 d = hist[(((size_t)(T_SEQ - 1) * 16 + gg * 4 + (p >> 9)) * 512 + (p & 511)) * 2];
    out[LOG + tid] = (float)u2h((unsigned short)(d >> ((pf & 3) * 16)));
    const size_t idx = (((size_t)(T_SEQ - 1) * 4 + gg) * 16 + kc) * 512 + (qd * 16 + m) * 8 + j;
    out[LOG + HL + tid] = (float)h1A[idx];
  }
}

extern "C" void kernel_launch(void* const* d_in, const int* in_sizes, int n_in,
                              void* d_out, int out_size, void* d_ws, size_t ws_size,
                              hipStream_t stream) {
  const int* x = (const int*)d_in[0];
  float* out = (float*)d_out;
  char* ws = (char*)d_ws;
  u64* ring = (u64*)(ws + OFF_RING);
  u64* hist = (u64*)(ws + OFF_HIST);
  _Float16* arena = (_Float16*)(ws + OFF_ARENA);
  _Float16* xw0f = (_Float16*)(ws + OFF_XW0);
  _Float16* h1A  = (_Float16*)(ws + OFF_H1A);

  canon_kernel<<<512, 256, 0, stream>>>(
      (const float*)d_in[1], (const float*)d_in[2], (const float*)d_in[3],
      (const float*)d_in[5], (const float*)d_in[6], (const float*)d_in[8],
      arena, (int*)ring);

  xw0_kernel<<<dim3(512, 8), 256, 0, stream>>>(
      x, arena + AOFF_EMB, arena + AOFF_WXH0, (const float*)d_in[4], xw0f);

  rnn_fused_kernel<<<32, 512, 0, stream>>>(
      arena + AOFF_WHH0, xw0f,
      arena + AOFF_WHH1, arena + AOFF_WXH1, (const float*)d_in[7],
      ring, hist, h1A);

  logits_kernel<<<512, 256, 0, stream>>>(
      h1A, arena + AOFF_WHY, (const float*)d_in[9], out);

  hlast_kernel<<<(BATCH * HID + 255) / 256, 256, 0, stream>>>(hist, h1A, out);
}